// Round 13
// baseline (758.518 us; speedup 1.0000x reference)
//
#include <hip/hip_runtime.h>
#include <math.h>

typedef float f32x4 __attribute__((ext_vector_type(4)));
typedef short s16x8 __attribute__((ext_vector_type(8)));
typedef unsigned short u16;

#define MFMA16(a,b,c) __builtin_amdgcn_mfma_f32_16x16x32_bf16((a),(b),(c),0,0,0)

__device__ __forceinline__ float bf2f(u16 u){
  union { unsigned int i; float f; } v; v.i = ((unsigned int)u)<<16; return v.f;
}
__device__ __forceinline__ u16 f2bf(float f){
  union { float f; unsigned int i; } v; v.f = f;
  unsigned int x = v.i;
  return (u16)((x + 0x7fffu + ((x>>16)&1u))>>16);
}

// ---------------------------------------------------------------------------
// Generic bf16 MFMA GEMM: C[M,N] = epilogue( A[M,K] @ B ), B given as BT[N,K].
// Tiles: BM=128, BN=64, BK=32; 256 threads = 4 waves.
// EPI_QKV also emits landmark means (16-token groups) for q and k.
// ---------------------------------------------------------------------------
enum { EPI_QKV=0, EPI_PINV=1, EPI_BIAS_RES=2, EPI_BIAS_GELU=3 };

template<int EPI>
__global__ __launch_bounds__(256)
void kgemm(const u16* __restrict__ A, const u16* __restrict__ BT, int K, int lda, int ldb,
           const float* __restrict__ bias, const float* __restrict__ base,
           float* __restrict__ resout,
           u16* __restrict__ outb, int ldc,
           u16* __restrict__ qo, u16* __restrict__ ko, u16* __restrict__ vo,
           u16* __restrict__ qlm, u16* __restrict__ klm)
{
  __shared__ __align__(16) u16 As[128][40];
  __shared__ __align__(16) u16 Bs[64][40];
  const int tid = threadIdx.x;
  const int w = tid>>6, l = tid&63, q = l>>4, ln = l&15;
  const int m0 = blockIdx.x*128, n0 = blockIdx.y*64;

  f32x4 acc[2][4];
  #pragma unroll
  for (int i=0;i<2;i++)
    #pragma unroll
    for (int j=0;j<4;j++){ acc[i][j][0]=0.f; acc[i][j][1]=0.f; acc[i][j][2]=0.f; acc[i][j][3]=0.f; }

  const int arow = tid>>2, aseg = tid&3;
  for (int k0=0; k0<K; k0+=32){
    *(int4*)&As[arow][aseg*8]    = *(const int4*)(A + (long)(m0+arow)*lda + k0 + aseg*8);
    *(int4*)&As[arow+64][aseg*8] = *(const int4*)(A + (long)(m0+arow+64)*lda + k0 + aseg*8);
    *(int4*)&Bs[arow][aseg*8]    = *(const int4*)(BT + (long)(n0+arow)*ldb + k0 + aseg*8);
    __syncthreads();
    s16x8 af[2], bfr[4];
    #pragma unroll
    for (int mt=0;mt<2;mt++) af[mt] = *(const s16x8*)&As[w*32 + mt*16 + ln][q*8];
    #pragma unroll
    for (int nt=0;nt<4;nt++) bfr[nt] = *(const s16x8*)&Bs[nt*16 + ln][q*8];
    #pragma unroll
    for (int mt=0;mt<2;mt++)
      #pragma unroll
      for (int nt=0;nt<4;nt++)
        acc[mt][nt] = MFMA16(af[mt], bfr[nt], acc[mt][nt]);
    __syncthreads();
  }

  #pragma unroll
  for (int mt=0;mt<2;mt++)
  #pragma unroll
  for (int nt=0;nt<4;nt++){
    if (EPI==EPI_QKV){
      int ncol = n0 + nt*16 + ln;
      int sel = ncol>>8, hd = ncol&255, h = hd>>5, d = hd&31;
      u16* dst = sel==0 ? qo : (sel==1 ? ko : vo);
      float sc = (sel==0) ? 0.17677669529663689f : 1.f;   // dh^-0.5 on q
      float s = 0.f;
      #pragma unroll
      for (int r=0;r<4;r++){
        int mrow = m0 + w*32 + mt*16 + q*4 + r;
        int b = mrow>>12, n = mrow&4095;
        float v = acc[mt][nt][r]*sc;
        dst[(((long)(b*8+h)*4096 + n)<<5) + d] = f2bf(v);
        s += v;
      }
      if (sel < 2){
        s += __shfl_xor(s, 16);
        s += __shfl_xor(s, 32);
        if (q == 0){
          int mrow0 = m0 + w*32 + mt*16;
          int b = mrow0>>12, grp = (mrow0&4095)>>4;
          u16* ldst = (sel==0) ? qlm : klm;
          ldst[(((long)(b*8+h)*256 + grp)<<5) + d] = f2bf(s*(1.0f/16.0f));
        }
      }
    } else {
      #pragma unroll
      for (int r=0;r<4;r++){
        int mrow = m0 + w*32 + mt*16 + q*4 + r;
        int ncol = n0 + nt*16 + ln;
        float v = acc[mt][nt][r];
        if (EPI==EPI_BIAS_RES){
          long idx = (long)mrow*ldc + ncol;
          resout[idx] = base[idx] + v + bias[ncol];
        } else if (EPI==EPI_BIAS_GELU){ // exact gelu
          float x = v + bias[ncol];
          float g = 0.5f*x*(1.0f + erff(x*0.70710678118654752f));
          outb[(long)mrow*ldc + ncol] = f2bf(g);
        } else {
          outb[(long)mrow*ldc + ncol] = f2bf(v);
        }
      }
    }
  }
}

// ---------------------------------------------------------------------------
// Batched pinv GEMM, 256-K per batch, BM=32 x BN=64 tiles (grid 1024/2048 WGs
// for square modes -> 4-8 WG/CU latency hiding; thin modes 256 WGs).
//  PM_W0  : W0 = X @ X^T * s0           grid (8,4,32)
//  PM_S   : S = W@W                     grid (8,4,32)
//  PM_M   : M = .25(13I-15W+7S-S@W)     grid (8,4,32)  [A=S,B=W; reads Wp,Sp]
//  PM_PAIR: W'=W@M / z'=z@M             grid (8,4,64)
//  PM_TH  : outT = (A@B)^T, B=T-layout  grid (8,1,32)  [thin: B stride 16384]
//  PM_THG : PM_TH + g1 epilogue: g1T = .25(13*w3T-15*aT+7*bT-cT)
//  PM_THINU: uT = (A@B)^T * s0, cols<32 grid (8,1,32)
// ---------------------------------------------------------------------------
enum { PM_W0=0, PM_S=1, PM_M=2, PM_PAIR=3, PM_TH=4, PM_THG=5, PM_THINU=6 };

template<int MODE>
__global__ __launch_bounds__(256)
void kpinv(const u16* __restrict__ A, const u16* __restrict__ B,
           const u16* __restrict__ A2,
           u16* __restrict__ out, u16* __restrict__ out2,
           const u16* __restrict__ Wp, const u16* __restrict__ Sp,
           const u16* __restrict__ Tp,
           const float* __restrict__ sptr)
{
  __shared__ __align__(16) u16 As[32][40];
  __shared__ __align__(16) u16 Bs[64][40];
  const int tid=threadIdx.x, w=tid>>6, l=tid&63, q=l>>4, ln=l&15;
  int bz = blockIdx.z, half = 0;
  if (MODE==PM_PAIR){ half = bz>>5; bz &= 31; }
  const u16* Ap = ((MODE==PM_PAIR && half) ? A2 : A) + (long)bz*65536;
  const long bstr = (MODE>=PM_TH) ? 16384 : 65536;
  const u16* Bp = B + (long)bz*bstr;
  const int m0 = blockIdx.x*32, n0 = blockIdx.y*64;
  float bscale = (MODE==PM_W0) ? *sptr : 1.f;

  f32x4 acc[2];
  #pragma unroll
  for (int j=0;j<2;j++){ acc[j][0]=0.f; acc[j][1]=0.f; acc[j][2]=0.f; acc[j][3]=0.f; }

  const int arw = tid>>3, acl = (tid&7)*4;
  const int brw = tid>>2, bcl = (tid&3)*8;
  for (int k0=0;k0<256;k0+=32){
    *(ushort4*)&As[arw][acl] = *(const ushort4*)(Ap + (long)(m0+arw)*256 + k0 + acl);
    if (MODE==PM_W0){
      int4 raw = *(const int4*)(Bp + (long)(n0+brw)*256 + k0 + bcl);
      u16* pr = (u16*)&raw; u16 o[8];
      #pragma unroll
      for (int j=0;j<8;j++) o[j] = f2bf(bscale*bf2f(pr[j]));
      *(int4*)&Bs[brw][bcl] = *(int4*)o;
    } else {
      *(int4*)&Bs[brw][bcl] = *(const int4*)(Bp + (long)(n0+brw)*256 + k0 + bcl);
    }
    __syncthreads();
    s16x8 bfr = *(const s16x8*)&Bs[w*16 + ln][q*8];
    #pragma unroll
    for (int mt=0;mt<2;mt++){
      s16x8 af = *(const s16x8*)&As[mt*16 + ln][q*8];
      acc[mt] = MFMA16(af, bfr, acc[mt]);
    }
    __syncthreads();
  }

  #pragma unroll
  for (int mt=0;mt<2;mt++)
  #pragma unroll
  for (int r=0;r<4;r++){
    int mrow = m0 + mt*16 + q*4 + r;
    int ncol = n0 + w*16 + ln;
    float v = acc[mt][r];
    long idx  = (long)bz*65536 + (long)mrow*256 + ncol;
    long idxt = (long)bz*16384 + (long)ncol*256 + mrow;
    if (MODE==PM_M){
      float wv = bf2f(Wp[idx]), sv = bf2f(Sp[idx]);
      float m = 0.25f*(((mrow==ncol)?13.f:0.f) - 15.f*wv + 7.f*sv - v);
      out[idx] = f2bf(m);
    } else if (MODE==PM_PAIR){
      (half ? out2 : out)[idx] = f2bf(v);
    } else if (MODE==PM_TH){
      out[idxt] = f2bf(v);
    } else if (MODE==PM_THG){
      float g = 0.25f*(13.f*bf2f(Wp[idxt]) - 15.f*bf2f(Sp[idxt]) + 7.f*bf2f(Tp[idxt]) - v);
      out[idxt] = f2bf(g);
    } else if (MODE==PM_THINU){
      if (ncol < 32) out[(long)bz*8192 + (long)ncol*256 + mrow] = f2bf(v*(*sptr));
    } else { // W0, S
      out[idx] = f2bf(v);
    }
  }
}

// ---------------------------------------------------------------------------
// LayerNorm: one wave per row (256 cols), write bf16
// ---------------------------------------------------------------------------
__global__ __launch_bounds__(256)
void kln(const float* __restrict__ y, const float* __restrict__ g, const float* __restrict__ b,
         u16* __restrict__ out)
{
  int w = threadIdx.x>>6, l = threadIdx.x&63;
  long row = (long)blockIdx.x*4 + w;
  float4 v = ((const float4*)(y + row*256))[l];
  float s = v.x+v.y+v.z+v.w;
  #pragma unroll
  for (int m=1;m<64;m<<=1) s += __shfl_xor(s, m);
  float mu = s*(1.0f/256.0f);
  float dx=v.x-mu, dy=v.y-mu, dz=v.z-mu, dw=v.w-mu;
  float s2 = dx*dx+dy*dy+dz*dz+dw*dw;
  #pragma unroll
  for (int m=1;m<64;m<<=1) s2 += __shfl_xor(s2, m);
  float rs = rsqrtf(s2*(1.0f/256.0f) + 1e-5f);
  float4 gg = ((const float4*)g)[l];
  float4 bb = ((const float4*)b)[l];
  ushort4 o;
  o.x = f2bf(dx*rs*gg.x + bb.x);
  o.y = f2bf(dy*rs*gg.y + bb.y);
  o.z = f2bf(dz*rs*gg.z + bb.z);
  o.w = f2bf(dw*rs*gg.w + bb.w);
  *(ushort4*)(out + row*256 + l*4) = o;
}

// ---------------------------------------------------------------------------
// Merged attn2 + attn3v (independent; grid (16,32): x<8 attn2, x>=8 attn3v)
// ---------------------------------------------------------------------------
__global__ __launch_bounds__(256)
void kattn23(const u16* __restrict__ ql, const u16* __restrict__ kl,
             u16* __restrict__ X, u16* __restrict__ XT, float* __restrict__ cs_p,
             const u16* __restrict__ kk, const u16* __restrict__ vv,
             float* __restrict__ num_p, float* __restrict__ den_p)
{
  __shared__ __align__(16) u16 Pbuf[4][64][40];
  __shared__ __align__(16) u16 vT[32][40];
  __shared__ float qrow[32][33];
  __shared__ float psum[32][4];
  __shared__ float rsum[32];
  int bh = blockIdx.y;
  int tid = threadIdx.x, w = tid>>6, l = tid&63, q = l>>4, ln = l&15;

  if (blockIdx.x < 8){
    int r0 = blockIdx.x*32;
    int c = tid;
    #pragma unroll
    for (int i=0;i<4;i++){
      int e = c*4+i; int rr = e>>5, dd = e&31;
      qrow[rr][dd] = bf2f(ql[((long)bh*256 + r0+rr)*32 + dd]);
    }
    float kc[32];
    {
      const u16* kp = kl + ((long)bh*256 + c)*32;
      #pragma unroll
      for (int d=0;d<32;d++) kc[d] = bf2f(kp[d]);
    }
    __syncthreads();
    float er[32]; float colacc = 0.f;
    for (int r=0;r<32;r++){
      float s = 0.f;
      #pragma unroll
      for (int d=0;d<32;d++) s += qrow[r][d]*kc[d];
      float e = __expf(s);
      er[r] = e;
      float wsum = e;
      #pragma unroll
      for (int m=1;m<64;m<<=1) wsum += __shfl_xor(wsum, m);
      if (l==0) psum[r][w] = wsum;
    }
    __syncthreads();
    if (c<32) rsum[c] = psum[c][0]+psum[c][1]+psum[c][2]+psum[c][3];
    __syncthreads();
    for (int r=0;r<32;r++){
      float x = er[r]/rsum[r];
      u16 xb = f2bf(x);
      X [((long)bh*256 + r0+r)*256 + c] = xb;
      XT[((long)bh*256 + c)*256 + r0+r] = xb;
      colacc += x;
    }
    cs_p[(long)blockIdx.x*8192 + bh*256 + c] = colacc;
    return;
  }

  int chunk = blockIdx.x - 8;
  f32x4 z4; z4[0]=0.f; z4[1]=0.f; z4[2]=0.f; z4[3]=0.f;
  f32x4 acc[4][2]; f32x4 dacc[4];
  #pragma unroll
  for (int mt=0;mt<4;mt++){ dacc[mt]=z4; acc[mt][0]=z4; acc[mt][1]=z4; }
  const u16* qlb = ql + (long)bh*8192;
  const u16* kb  = kk + (long)bh*131072;
  const u16* vb  = vv + (long)bh*131072;
  int vn = tid>>3, vd = (tid&7)*4;
  for (int s=0;s<16;s++){
    int n0 = chunk*512 + s*32;
    ushort4 vx = *(const ushort4*)(vb + (long)(n0+vn)*32 + vd);
    vT[vd+0][vn]=vx.x; vT[vd+1][vn]=vx.y; vT[vd+2][vn]=vx.z; vT[vd+3][vn]=vx.w;
    __syncthreads();
    s16x8 bk[2];
    #pragma unroll
    for (int nt=0;nt<2;nt++) bk[nt] = *(const s16x8*)(kb + (long)(n0 + nt*16 + ln)*32 + q*8);
    #pragma unroll
    for (int mt=0;mt<4;mt++){
      s16x8 aq = *(const s16x8*)(qlb + (long)(w*64 + mt*16 + ln)*32 + q*8);
      #pragma unroll
      for (int nt=0;nt<2;nt++){
        f32x4 sf = MFMA16(aq, bk[nt], z4);
        f32x4 ef;
        #pragma unroll
        for (int r=0;r<4;r++) ef[r] = __expf(sf[r]);
        dacc[mt] += ef;
        #pragma unroll
        for (int r=0;r<4;r++) Pbuf[w][mt*16 + q*4 + r][nt*16 + ln] = f2bf(ef[r]);
      }
    }
    #pragma unroll
    for (int mt=0;mt<4;mt++){
      s16x8 ap = *(const s16x8*)&Pbuf[w][mt*16 + ln][q*8];
      #pragma unroll
      for (int nt=0;nt<2;nt++){
        s16x8 bv = *(const s16x8*)&vT[nt*16 + ln][q*8];
        acc[mt][nt] = MFMA16(ap, bv, acc[mt][nt]);
      }
    }
    __syncthreads();
  }
  #pragma unroll
  for (int mt=0;mt<4;mt++)
    #pragma unroll
    for (int r=0;r<4;r++){
      float x = dacc[mt][r];
      x += __shfl_xor(x,1); x += __shfl_xor(x,2); x += __shfl_xor(x,4); x += __shfl_xor(x,8);
      dacc[mt][r] = x;
    }
  long pbase = (long)(chunk*32 + bh);
  #pragma unroll
  for (int mt=0;mt<4;mt++)
    #pragma unroll
    for (int nt=0;nt<2;nt++)
      #pragma unroll
      for (int r=0;r<4;r++){
        int mg = w*64 + mt*16 + q*4 + r;
        num_p[pbase*8192 + (long)mg*32 + nt*16 + ln] = acc[mt][nt][r];
      }
  if (ln==0){
    #pragma unroll
    for (int mt=0;mt<4;mt++)
      #pragma unroll
      for (int r=0;r<4;r++)
        den_p[pbase*256 + w*64 + mt*16 + q*4 + r] = dacc[mt][r];
  }
}

// ---------------------------------------------------------------------------
// ks0w3: WG0 = 1/max colsum; WG 1+bh = w3T prep (coalesced + LDS transpose)
// ---------------------------------------------------------------------------
__global__ __launch_bounds__(256)
void ks0w3(const float* __restrict__ cs_p, float* __restrict__ scal,
           const float* __restrict__ num_p, const float* __restrict__ den_p,
           u16* __restrict__ w3T)
{
  int t = threadIdx.x;
  if (blockIdx.x == 0){
    __shared__ float red[256];
    float m = 0.f;
    for (int i=t;i<8192;i+=256){
      float s = 0.f;
      #pragma unroll
      for (int c=0;c<8;c++) s += cs_p[(long)c*8192 + i];
      m = fmaxf(m, s);
    }
    red[t] = m; __syncthreads();
    for (int s=128;s>0;s>>=1){ if (t<s) red[t] = fmaxf(red[t], red[t+s]); __syncthreads(); }
    if (t==0) scal[0] = 1.0f/red[0];
    return;
  }
  int bh = blockIdx.x - 1;
  __shared__ float lt[32][257];
  for (int i=t;i<8192;i+=256){
    int m = i>>5, d = i&31;
    float sn = 0.f, sd = 0.f;
    #pragma unroll
    for (int c=0;c<8;c++){
      sn += num_p[((long)(c*32+bh))*8192 + i];
      sd += den_p[(c*32+bh)*256 + m];
    }
    lt[d][m] = sn/sd;
  }
  __syncthreads();
  u16* o = w3T + (long)bh*16384;
  for (int j=t;j<16384;j+=256){
    int d = j>>8, m = j&255;
    o[j] = (d<32) ? f2bf(lt[d][m]) : (u16)0;
  }
}

// ---------------------------------------------------------------------------
// attn1 fused + depthwise residual conv:
// aoutb = softmax(q @ k_l^T) @ u + conv33(v)
// ---------------------------------------------------------------------------
__global__ __launch_bounds__(256)
void kattn1u(const u16* __restrict__ qq, const u16* __restrict__ kl, const u16* __restrict__ uT,
             const u16* __restrict__ vv, const float* __restrict__ rw,
             u16* __restrict__ aoutb)
{
  int nch = blockIdx.x, bh = blockIdx.y;
  int b = bh>>3, h = bh&7;
  int tid = threadIdx.x, w = tid>>6, l = tid&63, q = l>>4, ln = l&15;
  __shared__ __align__(16) u16 Pbuf[4][32][40];
  __shared__ __align__(16) u16 vtile[160][36];
  int r0g = nch*128;
  const u16* vb = vv + (long)bh*131072;
  #pragma unroll
  for (int it=0; it<5; it++){
    int slot = tid + it*256;
    int rr = slot>>3, c = (slot&7)*4;
    int s = r0g - 16 + rr;
    ushort4 val; val.x=0; val.y=0; val.z=0; val.w=0;
    if (s>=0 && s<4096) val = *(const ushort4*)(vb + (long)s*32 + c);
    *(ushort4*)&vtile[rr][c] = val;
  }
  __syncthreads();

  f32x4 z4; z4[0]=0.f; z4[1]=0.f; z4[2]=0.f; z4[3]=0.f;
  f32x4 acc[2][2]; f32x4 dacc[2];
  #pragma unroll
  for (int mt=0;mt<2;mt++){ dacc[mt]=z4; acc[mt][0]=z4; acc[mt][1]=z4; }
  const u16* qb  = qq + (long)bh*131072;
  const u16* klb = kl + (long)bh*8192;
  const u16* ub  = uT + (long)bh*8192;
  int r0 = r0g + w*32;
  for (int s=0;s<8;s++){
    s16x8 bk[2];
    #pragma unroll
    for (int nt=0;nt<2;nt++) bk[nt] = *(const s16x8*)(klb + (long)(s*32 + nt*16 + ln)*32 + q*8);
    #pragma unroll
    for (int mt=0;mt<2;mt++){
      s16x8 aq = *(const s16x8*)(qb + (long)(r0 + mt*16 + ln)*32 + q*8);
      #pragma unroll
      for (int nt=0;nt<2;nt++){
        f32x4 sf = MFMA16(aq, bk[nt], z4);
        f32x4 ef;
        #pragma unroll
        for (int r=0;r<4;r++) ef[r] = __expf(sf[r]);
        dacc[mt] += ef;
        #pragma unroll
        for (int r=0;r<4;r++) Pbuf[w][mt*16 + q*4 + r][nt*16 + ln] = f2bf(ef[r]);
      }
    }
    #pragma unroll
    for (int mt=0;mt<2;mt++){
      s16x8 ap = *(const s16x8*)&Pbuf[w][mt*16 + ln][q*8];
      #pragma unroll
      for (int nt=0;nt<2;nt++){
        s16x8 bu = *(const s16x8*)(ub + (long)(nt*16 + ln)*256 + s*32 + q*8);
        acc[mt][nt] = MFMA16(ap, bu, acc[mt][nt]);
      }
    }
  }
  #pragma unroll
  for (int mt=0;mt<2;mt++)
    #pragma unroll
    for (int r=0;r<4;r++){
      float x = dacc[mt][r];
      x += __shfl_xor(x,1); x += __shfl_xor(x,2); x += __shfl_xor(x,4); x += __shfl_xor(x,8);
      dacc[mt][r] = x;
    }

  const float* wp = rw + h*33;
  float w_[33];
  #pragma unroll
  for (int j=0;j<33;j++) w_[j] = wp[j];

  #pragma unroll
  for (int mt=0;mt<2;mt++){
    int nl = w*32 + mt*16 + q*4;
    #pragma unroll
    for (int nt=0;nt<2;nt++){
      int d = nt*16 + ln;
      float vvv[36];
      #pragma unroll
      for (int j=0;j<36;j++) vvv[j] = bf2f(vtile[nl + j][d]);
      #pragma unroll
      for (int r=0;r<4;r++){
        float cv = 0.f;
        #pragma unroll
        for (int j=0;j<33;j++) cv += w_[j]*vvv[r+j];
        int n = r0 + mt*16 + q*4 + r;
        long oidx = ((long)b*4096 + n)*256 + h*32 + d;
        aoutb[oidx] = f2bf(acc[mt][nt][r]/dacc[mt][r] + cv);
      }
    }
  }
}

// ---------------------------------------------------------------------------
// Merged weight transpose+cast: all 4 weights in one launch (grid 1024).
// ---------------------------------------------------------------------------
__global__ __launch_bounds__(256)
void kcvtall(const float* __restrict__ wqkv, const float* __restrict__ wout,
             const float* __restrict__ w1, const float* __restrict__ w2,
             u16* __restrict__ wqkvT, u16* __restrict__ woutT,
             u16* __restrict__ w1T, u16* __restrict__ w2T)
{
  __shared__ float t[32][33];
  int z = blockIdx.x;
  const float* src; u16* dst; int K, Nn, bx, by;
  if (z < 384){      int i=z/192, r=z%192; src=wqkv+(long)i*196608; dst=wqkvT+(long)i*196608; K=256; Nn=768; bx=r%24; by=r/24; }
  else if (z < 512){ int zz=z-384; int i=zz/64, r=zz%64; src=wout+(long)i*65536; dst=woutT+(long)i*65536; K=256; Nn=256; bx=r%8; by=r/8; }
  else if (z < 768){ int zz=z-512; int i=zz/128, r=zz%128; src=w1+(long)i*131072; dst=w1T+(long)i*131072; K=256; Nn=512; bx=r%16; by=r/16; }
  else {             int zz=z-768; int i=zz/128, r=zz%128; src=w2+(long)i*131072; dst=w2T+(long)i*131072; K=512; Nn=256; bx=r%8; by=r/8; }
  int n0 = bx*32, k0 = by*32;
  int tx = threadIdx.x&31, ty = threadIdx.x>>5;
  #pragma unroll
  for (int i=0;i<4;i++) t[ty+i*8][tx] = src[(long)(k0+ty+i*8)*Nn + n0+tx];
  __syncthreads();
  #pragma unroll
  for (int i=0;i<4;i++) dst[(long)(n0+ty+i*8)*K + k0+tx] = f2bf(t[tx][ty+i*8]);
}

// ---------------------------------------------------------------------------
extern "C" void kernel_launch(void* const* d_in, const int* in_sizes, int n_in,
                              void* d_out, int out_size, void* d_ws, size_t ws_size,
                              hipStream_t stream)
{
  const float* x    = (const float*)d_in[0];
  const float* ln1g = (const float*)d_in[1];
  const float* ln1b = (const float*)d_in[2];
  const float* wqkv = (const float*)d_in[3];
  const float* wout = (const float*)d_in[4];
  const float* bout = (const float*)d_in[5];
  const float* resw = (const float*)d_in[6];
  const float* ln2g = (const float*)d_in[7];
  const float* ln2b = (const float*)d_in[8];
  const float* w1   = (const float*)d_in[9];
  const float* b1   = (const float*)d_in[10];
  const float* w2   = (const float*)d_in[11];
  const float* b2   = (const float*)d_in[12];
  float* y = (float*)d_out;
  char* ws = (char*)d_ws;

  u16* xn    = (u16*)(ws + 0);
  u16* qb    = (u16*)(ws + 8388608);
  u16* kb    = (u16*)(ws + 16777216);
  u16* vb    = (u16*)(ws + 25165824);
  u16* ql    = (u16*)(ws + 33554432);
  u16* kl    = (u16*)(ws + 34078720);
  u16* X     = (u16*)(ws + 34603008);
  u16* XT    = (u16*)(ws + 38797312);     // doubles as z~0
  u16* w3T   = (u16*)(ws + 42991616);     // [32][64][256] bf16 (rows>=32 zero)
  u16* g1T   = (u16*)(ws + 44040192);     // [32][64][256] bf16
  u16* aT    = (u16*)(ws + 45088768);     // [32][64][256]
  u16* bT    = (u16*)(ws + 46137344);     // [32][64][256]
  // pinv work region: 6 x 4 MB
  u16* WA    = (u16*)(ws + 51380224);
  u16* WB    = (u16*)(ws + 55574528);
  u16* Sb    = (u16*)(ws + 59768832);
  u16* Mb    = (u16*)(ws + 63963136);
  u16* zA    = (u16*)(ws + 68157440);
  u16* zB    = (u16*)(ws + 72351744);
  float* num_p = (float*)(ws + 76546048);  // 8 MB: [8][32][256][32]
  float* den_p = (float*)(ws + 84934656);  // 256 KB
  float* cs_p  = (float*)(ws + 85196800);  // 256 KB
  float* scal  = (float*)(ws + 85458944);
  u16* uT    = (u16*)(ws + 85459200);
  u16* aoutb = (u16*)(ws + 85983488);
  u16* wqkvT = (u16*)(ws + 94372096);
  u16* woutT = (u16*)(ws + 95158528);
  u16* w1T   = (u16*)(ws + 95420672);
  u16* w2T   = (u16*)(ws + 95944960);
  u16* hdn   = (u16*)(ws + 51380224);      // overlays pinv region (dead by FFN)

  (void)in_sizes; (void)n_in; (void)out_size; (void)ws_size;

  kcvtall<<<1024,256,0,stream>>>(wqkv, wout, w1, w2, wqkvT, woutT, w1T, w2T);

  for (int i=0;i<2;i++){
    kln<<<4096,256,0,stream>>>(i==0 ? x : y, ln1g + i*256, ln1b + i*256, xn);
    kgemm<EPI_QKV><<<dim3(128,12,1),256,0,stream>>>(xn, wqkvT + (long)i*196608, 256, 256, 256,
        nullptr,nullptr,nullptr,nullptr,0, qb,kb,vb, ql,kl);
    kattn23<<<dim3(16,32),256,0,stream>>>(ql, kl, X, XT, cs_p, kb, vb, num_p, den_p);
    ks0w3<<<33,256,0,stream>>>(cs_p, scal, num_p, den_p, w3T);

    // ---- pinv: W' = W@M, z~' = z~@M with M = 0.25(13I - 15W + 7S - S@W) ----
    kpinv<PM_W0><<<dim3(8,4,32),256,0,stream>>>(X, X, nullptr, WA, nullptr,
        nullptr, nullptr, nullptr, scal);
    u16 *Wi = WA, *Wo = WB, *zi = XT, *zo = zA;
    for (int it=0; it<5; it++){
      kpinv<PM_S><<<dim3(8,4,32),256,0,stream>>>(Wi, Wi, nullptr, Sb, nullptr,
          nullptr, nullptr, nullptr, nullptr);
      kpinv<PM_M><<<dim3(8,4,32),256,0,stream>>>(Sb, Wi, nullptr, Mb, nullptr,
          Wi, Sb, nullptr, nullptr);
      kpinv<PM_PAIR><<<dim3(8,4,64),256,0,stream>>>(Wi, Mb, zi, Wo, zo,
          nullptr, nullptr, nullptr, nullptr);
      u16* t = Wi; Wi = Wo; Wo = t;
      zi = zo; zo = (zo == zA) ? zB : zA;
    }
    // thin tail (iteration 6 applied to w3 only):
    // a=W5@w3, b=W5@a, c=W5@b with g1 = .25(13w3-15a+7b-c); u = z5@g1 * s0
    kpinv<PM_TH><<<dim3(8,1,32),256,0,stream>>>(Wi, w3T, nullptr, aT, nullptr,
        nullptr, nullptr, nullptr, nullptr);
    kpinv<PM_TH><<<dim3(8,1,32),256,0,stream>>>(Wi, aT, nullptr, bT, nullptr,
        nullptr, nullptr, nullptr, nullptr);
    kpinv<PM_THG><<<dim3(8,1,32),256,0,stream>>>(Wi, bT, nullptr, g1T, nullptr,
        w3T, aT, bT, nullptr);
    kpinv<PM_THINU><<<dim3(8,1,32),256,0,stream>>>(zi, g1T, nullptr, uT, nullptr,
        nullptr, nullptr, nullptr, scal);

    kattn1u<<<dim3(32,32),256,0,stream>>>(qb, kl, uT, vb, resw + i*264, aoutb);
    kgemm<EPI_BIAS_RES><<<dim3(128,4,1),256,0,stream>>>(aoutb, woutT + (long)i*65536, 256,256,256,
        bout + i*256, i==0 ? x : y, y, nullptr, 256, nullptr,nullptr,nullptr, nullptr,nullptr);
    kln<<<4096,256,0,stream>>>(y, ln2g + i*256, ln2b + i*256, xn);
    kgemm<EPI_BIAS_GELU><<<dim3(128,8,1),256,0,stream>>>(xn, w1T + (long)i*131072, 256,256,256,
        b1 + i*512, nullptr, nullptr, hdn, 512, nullptr,nullptr,nullptr, nullptr,nullptr);
    kgemm<EPI_BIAS_RES><<<dim3(128,4,1),256,0,stream>>>(hdn, w2T + (long)i*131072, 512,512,512,
        b2 + i*256, y, y, nullptr, 256, nullptr,nullptr,nullptr, nullptr,nullptr);
  }
}

// Round 14
// 732.231 us; speedup vs baseline: 1.0359x; 1.0359x over previous
//
#include <hip/hip_runtime.h>
#include <math.h>

typedef float f32x4 __attribute__((ext_vector_type(4)));
typedef short s16x8 __attribute__((ext_vector_type(8)));
typedef unsigned short u16;

#define MFMA16(a,b,c) __builtin_amdgcn_mfma_f32_16x16x32_bf16((a),(b),(c),0,0,0)

__device__ __forceinline__ float bf2f(u16 u){
  union { unsigned int i; float f; } v; v.i = ((unsigned int)u)<<16; return v.f;
}
__device__ __forceinline__ u16 f2bf(float f){
  union { float f; unsigned int i; } v; v.f = f;
  unsigned int x = v.i;
  return (u16)((x + 0x7fffu + ((x>>16)&1u))>>16);
}

enum { EPI_QKV=0, EPI_PINV=1, EPI_BIAS_RES=2, EPI_BIAS_GELU=3 };

// ---------------------------------------------------------------------------
// kgemm: BM=128, BN=64, BK=32 (for N=256 outputs: RES / RES2)
// ---------------------------------------------------------------------------
template<int EPI>
__global__ __launch_bounds__(256)
void kgemm(const u16* __restrict__ A, const u16* __restrict__ BT, int K, int lda, int ldb,
           const float* __restrict__ bias, const float* __restrict__ base,
           float* __restrict__ resout,
           u16* __restrict__ outb, int ldc)
{
  __shared__ __align__(16) u16 As[128][40];
  __shared__ __align__(16) u16 Bs[64][40];
  const int tid = threadIdx.x;
  const int w = tid>>6, l = tid&63, q = l>>4, ln = l&15;
  const int m0 = blockIdx.x*128, n0 = blockIdx.y*64;

  f32x4 acc[2][4];
  #pragma unroll
  for (int i=0;i<2;i++)
    #pragma unroll
    for (int j=0;j<4;j++){ acc[i][j][0]=0.f; acc[i][j][1]=0.f; acc[i][j][2]=0.f; acc[i][j][3]=0.f; }

  const int arow = tid>>2, aseg = tid&3;
  for (int k0=0; k0<K; k0+=32){
    *(int4*)&As[arow][aseg*8]    = *(const int4*)(A + (long)(m0+arow)*lda + k0 + aseg*8);
    *(int4*)&As[arow+64][aseg*8] = *(const int4*)(A + (long)(m0+arow+64)*lda + k0 + aseg*8);
    *(int4*)&Bs[arow][aseg*8]    = *(const int4*)(BT + (long)(n0+arow)*ldb + k0 + aseg*8);
    __syncthreads();
    s16x8 af[2], bfr[4];
    #pragma unroll
    for (int mt=0;mt<2;mt++) af[mt] = *(const s16x8*)&As[w*32 + mt*16 + ln][q*8];
    #pragma unroll
    for (int nt=0;nt<4;nt++) bfr[nt] = *(const s16x8*)&Bs[nt*16 + ln][q*8];
    #pragma unroll
    for (int mt=0;mt<2;mt++)
      #pragma unroll
      for (int nt=0;nt<4;nt++)
        acc[mt][nt] = MFMA16(af[mt], bfr[nt], acc[mt][nt]);
    __syncthreads();
  }

  #pragma unroll
  for (int mt=0;mt<2;mt++)
  #pragma unroll
  for (int nt=0;nt<4;nt++)
  #pragma unroll
  for (int r=0;r<4;r++){
    int mrow = m0 + w*32 + mt*16 + q*4 + r;
    int ncol = n0 + nt*16 + ln;
    float v = acc[mt][nt][r];
    if (EPI==EPI_BIAS_RES){
      long idx = (long)mrow*ldc + ncol;
      resout[idx] = base[idx] + v + bias[ncol];
    } else {
      outb[(long)mrow*ldc + ncol] = f2bf(v);
    }
  }
}

// ---------------------------------------------------------------------------
// kgemm2: BM=128, BN=128, BK=32, 4x4 frags/wave (2x2 wave grid) — LDS-lean.
// For wide GEMMs: QKV (N=768) and FFN1+GELU (N=512).
// EPI_QKV also emits landmark means.
// ---------------------------------------------------------------------------
template<int EPI>
__global__ __launch_bounds__(256)
void kgemm2(const u16* __restrict__ A, const u16* __restrict__ BT, int K, int lda, int ldb,
            const float* __restrict__ bias, u16* __restrict__ outb, int ldc,
            u16* __restrict__ qo, u16* __restrict__ ko, u16* __restrict__ vo,
            u16* __restrict__ qlm, u16* __restrict__ klm)
{
  __shared__ __align__(16) u16 As[128][40];
  __shared__ __align__(16) u16 Bs[128][40];
  const int tid = threadIdx.x;
  const int w = tid>>6, wy = w>>1, wx = w&1, l = tid&63, q = l>>4, ln = l&15;
  const int m0 = blockIdx.x*128, n0 = blockIdx.y*128;

  f32x4 acc[4][4];
  #pragma unroll
  for (int i=0;i<4;i++)
    #pragma unroll
    for (int j=0;j<4;j++){ acc[i][j][0]=0.f; acc[i][j][1]=0.f; acc[i][j][2]=0.f; acc[i][j][3]=0.f; }

  const int srow = tid>>1, sc = (tid&1)*16;
  for (int k0=0; k0<K; k0+=32){
    *(int4*)&As[srow][sc]   = *(const int4*)(A + (long)(m0+srow)*lda + k0 + sc);
    *(int4*)&As[srow][sc+8] = *(const int4*)(A + (long)(m0+srow)*lda + k0 + sc + 8);
    *(int4*)&Bs[srow][sc]   = *(const int4*)(BT + (long)(n0+srow)*ldb + k0 + sc);
    *(int4*)&Bs[srow][sc+8] = *(const int4*)(BT + (long)(n0+srow)*ldb + k0 + sc + 8);
    __syncthreads();
    s16x8 af[4], bfr[4];
    #pragma unroll
    for (int mt=0;mt<4;mt++) af[mt] = *(const s16x8*)&As[wy*64 + mt*16 + ln][q*8];
    #pragma unroll
    for (int nt=0;nt<4;nt++) bfr[nt] = *(const s16x8*)&Bs[wx*64 + nt*16 + ln][q*8];
    #pragma unroll
    for (int mt=0;mt<4;mt++)
      #pragma unroll
      for (int nt=0;nt<4;nt++)
        acc[mt][nt] = MFMA16(af[mt], bfr[nt], acc[mt][nt]);
    __syncthreads();
  }

  #pragma unroll
  for (int mt=0;mt<4;mt++)
  #pragma unroll
  for (int nt=0;nt<4;nt++){
    int ncol = n0 + wx*64 + nt*16 + ln;
    if (EPI==EPI_QKV){
      int sel = ncol>>8, hd = ncol&255, h = hd>>5, d = hd&31;
      u16* dst = sel==0 ? qo : (sel==1 ? ko : vo);
      float sc2 = (sel==0) ? 0.17677669529663689f : 1.f;   // dh^-0.5 on q
      float s = 0.f;
      #pragma unroll
      for (int r=0;r<4;r++){
        int mrow = m0 + wy*64 + mt*16 + q*4 + r;
        int b = mrow>>12, n = mrow&4095;
        float v = acc[mt][nt][r]*sc2;
        dst[(((long)(b*8+h)*4096 + n)<<5) + d] = f2bf(v);
        s += v;
      }
      if (sel < 2){
        s += __shfl_xor(s, 16);
        s += __shfl_xor(s, 32);
        if (q == 0){
          int mrow0 = m0 + wy*64 + mt*16;
          int b = mrow0>>12, grp = (mrow0&4095)>>4;
          u16* ldst = (sel==0) ? qlm : klm;
          ldst[(((long)(b*8+h)*256 + grp)<<5) + d] = f2bf(s*(1.0f/16.0f));
        }
      }
    } else { // EPI_BIAS_GELU
      #pragma unroll
      for (int r=0;r<4;r++){
        int mrow = m0 + wy*64 + mt*16 + q*4 + r;
        float x = acc[mt][nt][r] + bias[ncol];
        float g = 0.5f*x*(1.0f + erff(x*0.70710678118654752f));
        outb[(long)mrow*ldc + ncol] = f2bf(g);
      }
    }
  }
}

// ---------------------------------------------------------------------------
// Batched pinv GEMM, 256-K per batch, 64x64 tiles BK=32 (round-12 proven).
//  PM_W0/S/M/PAIR: square modes, grids (4,4,32)/(4,4,64)
//  PM_TH  : outT = (A@B)^T        grid (4,1,32), B stride 16384
//  PM_THG : PM_TH + g1 epilogue: g1T = .25(13*w3T-15*aT+7*bT-cT)
//  PM_THINU: uT = (A@B)^T * s0, cols<32
// ---------------------------------------------------------------------------
enum { PM_W0=0, PM_S=1, PM_M=2, PM_PAIR=3, PM_TH=4, PM_THG=5, PM_THINU=6 };

template<int MODE>
__global__ __launch_bounds__(256)
void kpinv(const u16* __restrict__ A, const u16* __restrict__ B,
           const u16* __restrict__ A2,
           u16* __restrict__ out, u16* __restrict__ out2,
           const u16* __restrict__ Wp, const u16* __restrict__ Sp,
           const u16* __restrict__ Tp,
           const float* __restrict__ sptr)
{
  __shared__ __align__(16) u16 As[64][40];
  __shared__ __align__(16) u16 Bs[64][40];
  const int tid=threadIdx.x, w=tid>>6, l=tid&63, q=l>>4, ln=l&15;
  int bz = blockIdx.z, half = 0;
  if (MODE==PM_PAIR){ half = bz>>5; bz &= 31; }
  const u16* Ap = ((MODE==PM_PAIR && half) ? A2 : A) + (long)bz*65536;
  const long bstr = (MODE>=PM_TH) ? 16384 : 65536;
  const u16* Bp = B + (long)bz*bstr;
  const int m0 = blockIdx.x*64, n0 = blockIdx.y*64;
  float bscale = (MODE==PM_W0) ? *sptr : 1.f;

  f32x4 acc[4];
  #pragma unroll
  for (int j=0;j<4;j++){ acc[j][0]=0.f; acc[j][1]=0.f; acc[j][2]=0.f; acc[j][3]=0.f; }

  const int srow = tid>>2, sseg = tid&3;
  for (int k0=0;k0<256;k0+=32){
    *(int4*)&As[srow][sseg*8] = *(const int4*)(Ap + (long)(m0+srow)*256 + k0 + sseg*8);
    if (MODE==PM_W0){
      int4 raw = *(const int4*)(Bp + (long)(n0+srow)*256 + k0 + sseg*8);
      u16* pr = (u16*)&raw; u16 o[8];
      #pragma unroll
      for (int j=0;j<8;j++) o[j] = f2bf(bscale*bf2f(pr[j]));
      *(int4*)&Bs[srow][sseg*8] = *(int4*)o;
    } else {
      *(int4*)&Bs[srow][sseg*8] = *(const int4*)(Bp + (long)(n0+srow)*256 + k0 + sseg*8);
    }
    __syncthreads();
    s16x8 af = *(const s16x8*)&As[w*16 + ln][q*8];
    #pragma unroll
    for (int nt=0;nt<4;nt++){
      s16x8 bfr = *(const s16x8*)&Bs[nt*16 + ln][q*8];
      acc[nt] = MFMA16(af, bfr, acc[nt]);
    }
    __syncthreads();
  }

  #pragma unroll
  for (int nt=0;nt<4;nt++)
  #pragma unroll
  for (int r=0;r<4;r++){
    int mrow = m0 + w*16 + q*4 + r;
    int ncol = n0 + nt*16 + ln;
    float v = acc[nt][r];
    long idx  = (long)bz*65536 + (long)mrow*256 + ncol;
    long idxt = (long)bz*16384 + (long)ncol*256 + mrow;
    if (MODE==PM_M){
      float wv = bf2f(Wp[idx]), sv = bf2f(Sp[idx]);
      float m = 0.25f*(((mrow==ncol)?13.f:0.f) - 15.f*wv + 7.f*sv - v);
      out[idx] = f2bf(m);
    } else if (MODE==PM_PAIR){
      (half ? out2 : out)[idx] = f2bf(v);
    } else if (MODE==PM_TH){
      out[idxt] = f2bf(v);
    } else if (MODE==PM_THG){
      float g = 0.25f*(13.f*bf2f(Wp[idxt]) - 15.f*bf2f(Sp[idxt]) + 7.f*bf2f(Tp[idxt]) - v);
      out[idxt] = f2bf(g);
    } else if (MODE==PM_THINU){
      if (ncol < 32) out[(long)bz*8192 + (long)ncol*256 + mrow] = f2bf(v*(*sptr));
    } else { // W0, S
      out[idx] = f2bf(v);
    }
  }
}

// ---------------------------------------------------------------------------
// LayerNorm: one wave per row (256 cols), write bf16
// ---------------------------------------------------------------------------
__global__ __launch_bounds__(256)
void kln(const float* __restrict__ y, const float* __restrict__ g, const float* __restrict__ b,
         u16* __restrict__ out)
{
  int w = threadIdx.x>>6, l = threadIdx.x&63;
  long row = (long)blockIdx.x*4 + w;
  float4 v = ((const float4*)(y + row*256))[l];
  float s = v.x+v.y+v.z+v.w;
  #pragma unroll
  for (int m=1;m<64;m<<=1) s += __shfl_xor(s, m);
  float mu = s*(1.0f/256.0f);
  float dx=v.x-mu, dy=v.y-mu, dz=v.z-mu, dw=v.w-mu;
  float s2 = dx*dx+dy*dy+dz*dz+dw*dw;
  #pragma unroll
  for (int m=1;m<64;m<<=1) s2 += __shfl_xor(s2, m);
  float rs = rsqrtf(s2*(1.0f/256.0f) + 1e-5f);
  float4 gg = ((const float4*)g)[l];
  float4 bb = ((const float4*)b)[l];
  ushort4 o;
  o.x = f2bf(dx*rs*gg.x + bb.x);
  o.y = f2bf(dy*rs*gg.y + bb.y);
  o.z = f2bf(dz*rs*gg.z + bb.z);
  o.w = f2bf(dw*rs*gg.w + bb.w);
  *(ushort4*)(out + row*256 + l*4) = o;
}

// ---------------------------------------------------------------------------
// Merged attn2 + attn3v (independent; grid (16,32): x<8 attn2, x>=8 attn3v)
// ---------------------------------------------------------------------------
__global__ __launch_bounds__(256)
void kattn23(const u16* __restrict__ ql, const u16* __restrict__ kl,
             u16* __restrict__ X, u16* __restrict__ XT, float* __restrict__ cs_p,
             const u16* __restrict__ kk, const u16* __restrict__ vv,
             float* __restrict__ num_p, float* __restrict__ den_p)
{
  __shared__ __align__(16) u16 Pbuf[4][64][40];
  __shared__ __align__(16) u16 vT[32][40];
  __shared__ float qrow[32][33];
  __shared__ float psum[32][4];
  __shared__ float rsum[32];
  int bh = blockIdx.y;
  int tid = threadIdx.x, w = tid>>6, l = tid&63, q = l>>4, ln = l&15;

  if (blockIdx.x < 8){
    int r0 = blockIdx.x*32;
    int c = tid;
    #pragma unroll
    for (int i=0;i<4;i++){
      int e = c*4+i; int rr = e>>5, dd = e&31;
      qrow[rr][dd] = bf2f(ql[((long)bh*256 + r0+rr)*32 + dd]);
    }
    float kc[32];
    {
      const u16* kp = kl + ((long)bh*256 + c)*32;
      #pragma unroll
      for (int d=0;d<32;d++) kc[d] = bf2f(kp[d]);
    }
    __syncthreads();
    float er[32]; float colacc = 0.f;
    for (int r=0;r<32;r++){
      float s = 0.f;
      #pragma unroll
      for (int d=0;d<32;d++) s += qrow[r][d]*kc[d];
      float e = __expf(s);
      er[r] = e;
      float wsum = e;
      #pragma unroll
      for (int m=1;m<64;m<<=1) wsum += __shfl_xor(wsum, m);
      if (l==0) psum[r][w] = wsum;
    }
    __syncthreads();
    if (c<32) rsum[c] = psum[c][0]+psum[c][1]+psum[c][2]+psum[c][3];
    __syncthreads();
    for (int r=0;r<32;r++){
      float x = er[r]/rsum[r];
      u16 xb = f2bf(x);
      X [((long)bh*256 + r0+r)*256 + c] = xb;
      XT[((long)bh*256 + c)*256 + r0+r] = xb;
      colacc += x;
    }
    cs_p[(long)blockIdx.x*8192 + bh*256 + c] = colacc;
    return;
  }

  int chunk = blockIdx.x - 8;
  f32x4 z4; z4[0]=0.f; z4[1]=0.f; z4[2]=0.f; z4[3]=0.f;
  f32x4 acc[4][2]; f32x4 dacc[4];
  #pragma unroll
  for (int mt=0;mt<4;mt++){ dacc[mt]=z4; acc[mt][0]=z4; acc[mt][1]=z4; }
  const u16* qlb = ql + (long)bh*8192;
  const u16* kb  = kk + (long)bh*131072;
  const u16* vb  = vv + (long)bh*131072;
  int vn = tid>>3, vd = (tid&7)*4;
  for (int s=0;s<16;s++){
    int n0 = chunk*512 + s*32;
    ushort4 vx = *(const ushort4*)(vb + (long)(n0+vn)*32 + vd);
    vT[vd+0][vn]=vx.x; vT[vd+1][vn]=vx.y; vT[vd+2][vn]=vx.z; vT[vd+3][vn]=vx.w;
    __syncthreads();
    s16x8 bk[2];
    #pragma unroll
    for (int nt=0;nt<2;nt++) bk[nt] = *(const s16x8*)(kb + (long)(n0 + nt*16 + ln)*32 + q*8);
    #pragma unroll
    for (int mt=0;mt<4;mt++){
      s16x8 aq = *(const s16x8*)(qlb + (long)(w*64 + mt*16 + ln)*32 + q*8);
      #pragma unroll
      for (int nt=0;nt<2;nt++){
        f32x4 sf = MFMA16(aq, bk[nt], z4);
        f32x4 ef;
        #pragma unroll
        for (int r=0;r<4;r++) ef[r] = __expf(sf[r]);
        dacc[mt] += ef;
        #pragma unroll
        for (int r=0;r<4;r++) Pbuf[w][mt*16 + q*4 + r][nt*16 + ln] = f2bf(ef[r]);
      }
    }
    #pragma unroll
    for (int mt=0;mt<4;mt++){
      s16x8 ap = *(const s16x8*)&Pbuf[w][mt*16 + ln][q*8];
      #pragma unroll
      for (int nt=0;nt<2;nt++){
        s16x8 bv = *(const s16x8*)&vT[nt*16 + ln][q*8];
        acc[mt][nt] = MFMA16(ap, bv, acc[mt][nt]);
      }
    }
    __syncthreads();
  }
  #pragma unroll
  for (int mt=0;mt<4;mt++)
    #pragma unroll
    for (int r=0;r<4;r++){
      float x = dacc[mt][r];
      x += __shfl_xor(x,1); x += __shfl_xor(x,2); x += __shfl_xor(x,4); x += __shfl_xor(x,8);
      dacc[mt][r] = x;
    }
  long pbase = (long)(chunk*32 + bh);
  #pragma unroll
  for (int mt=0;mt<4;mt++)
    #pragma unroll
    for (int nt=0;nt<2;nt++)
      #pragma unroll
      for (int r=0;r<4;r++){
        int mg = w*64 + mt*16 + q*4 + r;
        num_p[pbase*8192 + (long)mg*32 + nt*16 + ln] = acc[mt][nt][r];
      }
  if (ln==0){
    #pragma unroll
    for (int mt=0;mt<4;mt++)
      #pragma unroll
      for (int r=0;r<4;r++)
        den_p[pbase*256 + w*64 + mt*16 + q*4 + r] = dacc[mt][r];
  }
}

// ---------------------------------------------------------------------------
// ks0w3: WG0 = 1/max colsum; WG 1+bh = w3T prep (coalesced + LDS transpose)
// ---------------------------------------------------------------------------
__global__ __launch_bounds__(256)
void ks0w3(const float* __restrict__ cs_p, float* __restrict__ scal,
           const float* __restrict__ num_p, const float* __restrict__ den_p,
           u16* __restrict__ w3T)
{
  int t = threadIdx.x;
  if (blockIdx.x == 0){
    __shared__ float red[256];
    float m = 0.f;
    for (int i=t;i<8192;i+=256){
      float s = 0.f;
      #pragma unroll
      for (int c=0;c<8;c++) s += cs_p[(long)c*8192 + i];
      m = fmaxf(m, s);
    }
    red[t] = m; __syncthreads();
    for (int s=128;s>0;s>>=1){ if (t<s) red[t] = fmaxf(red[t], red[t+s]); __syncthreads(); }
    if (t==0) scal[0] = 1.0f/red[0];
    return;
  }
  int bh = blockIdx.x - 1;
  __shared__ float lt[32][257];
  for (int i=t;i<8192;i+=256){
    int m = i>>5, d = i&31;
    float sn = 0.f, sd = 0.f;
    #pragma unroll
    for (int c=0;c<8;c++){
      sn += num_p[((long)(c*32+bh))*8192 + i];
      sd += den_p[(c*32+bh)*256 + m];
    }
    lt[d][m] = sn/sd;
  }
  __syncthreads();
  u16* o = w3T + (long)bh*16384;
  for (int j=t;j<16384;j+=256){
    int d = j>>8, m = j&255;
    o[j] = (d<32) ? f2bf(lt[d][m]) : (u16)0;
  }
}

// ---------------------------------------------------------------------------
// attn1 fused + depthwise residual conv:
// aoutb = softmax(q @ k_l^T) @ u + conv33(v)
// ---------------------------------------------------------------------------
__global__ __launch_bounds__(256)
void kattn1u(const u16* __restrict__ qq, const u16* __restrict__ kl, const u16* __restrict__ uT,
             const u16* __restrict__ vv, const float* __restrict__ rw,
             u16* __restrict__ aoutb)
{
  int nch = blockIdx.x, bh = blockIdx.y;
  int b = bh>>3, h = bh&7;
  int tid = threadIdx.x, w = tid>>6, l = tid&63, q = l>>4, ln = l&15;
  __shared__ __align__(16) u16 Pbuf[4][32][40];
  __shared__ __align__(16) u16 vtile[160][36];
  int r0g = nch*128;
  const u16* vb = vv + (long)bh*131072;
  #pragma unroll
  for (int it=0; it<5; it++){
    int slot = tid + it*256;
    int rr = slot>>3, c = (slot&7)*4;
    int s = r0g - 16 + rr;
    ushort4 val; val.x=0; val.y=0; val.z=0; val.w=0;
    if (s>=0 && s<4096) val = *(const ushort4*)(vb + (long)s*32 + c);
    *(ushort4*)&vtile[rr][c] = val;
  }
  __syncthreads();

  f32x4 z4; z4[0]=0.f; z4[1]=0.f; z4[2]=0.f; z4[3]=0.f;
  f32x4 acc[2][2]; f32x4 dacc[2];
  #pragma unroll
  for (int mt=0;mt<2;mt++){ dacc[mt]=z4; acc[mt][0]=z4; acc[mt][1]=z4; }
  const u16* qb  = qq + (long)bh*131072;
  const u16* klb = kl + (long)bh*8192;
  const u16* ub  = uT + (long)bh*8192;
  int r0 = r0g + w*32;
  for (int s=0;s<8;s++){
    s16x8 bk[2];
    #pragma unroll
    for (int nt=0;nt<2;nt++) bk[nt] = *(const s16x8*)(klb + (long)(s*32 + nt*16 + ln)*32 + q*8);
    #pragma unroll
    for (int mt=0;mt<2;mt++){
      s16x8 aq = *(const s16x8*)(qb + (long)(r0 + mt*16 + ln)*32 + q*8);
      #pragma unroll
      for (int nt=0;nt<2;nt++){
        f32x4 sf = MFMA16(aq, bk[nt], z4);
        f32x4 ef;
        #pragma unroll
        for (int r=0;r<4;r++) ef[r] = __expf(sf[r]);
        dacc[mt] += ef;
        #pragma unroll
        for (int r=0;r<4;r++) Pbuf[w][mt*16 + q*4 + r][nt*16 + ln] = f2bf(ef[r]);
      }
    }
    #pragma unroll
    for (int mt=0;mt<2;mt++){
      s16x8 ap = *(const s16x8*)&Pbuf[w][mt*16 + ln][q*8];
      #pragma unroll
      for (int nt=0;nt<2;nt++){
        s16x8 bu = *(const s16x8*)(ub + (long)(nt*16 + ln)*256 + s*32 + q*8);
        acc[mt][nt] = MFMA16(ap, bu, acc[mt][nt]);
      }
    }
  }
  #pragma unroll
  for (int mt=0;mt<2;mt++)
    #pragma unroll
    for (int r=0;r<4;r++){
      float x = dacc[mt][r];
      x += __shfl_xor(x,1); x += __shfl_xor(x,2); x += __shfl_xor(x,4); x += __shfl_xor(x,8);
      dacc[mt][r] = x;
    }

  const float* wp = rw + h*33;
  float w_[33];
  #pragma unroll
  for (int j=0;j<33;j++) w_[j] = wp[j];

  #pragma unroll
  for (int mt=0;mt<2;mt++){
    int nl = w*32 + mt*16 + q*4;
    #pragma unroll
    for (int nt=0;nt<2;nt++){
      int d = nt*16 + ln;
      float vvv[36];
      #pragma unroll
      for (int j=0;j<36;j++) vvv[j] = bf2f(vtile[nl + j][d]);
      #pragma unroll
      for (int r=0;r<4;r++){
        float cv = 0.f;
        #pragma unroll
        for (int j=0;j<33;j++) cv += w_[j]*vvv[r+j];
        int n = r0 + mt*16 + q*4 + r;
        long oidx = ((long)b*4096 + n)*256 + h*32 + d;
        aoutb[oidx] = f2bf(acc[mt][nt][r]/dacc[mt][r] + cv);
      }
    }
  }
}

// ---------------------------------------------------------------------------
// Merged weight transpose+cast: all 4 weights in one launch (grid 1024).
// ---------------------------------------------------------------------------
__global__ __launch_bounds__(256)
void kcvtall(const float* __restrict__ wqkv, const float* __restrict__ wout,
             const float* __restrict__ w1, const float* __restrict__ w2,
             u16* __restrict__ wqkvT, u16* __restrict__ woutT,
             u16* __restrict__ w1T, u16* __restrict__ w2T)
{
  __shared__ float t[32][33];
  int z = blockIdx.x;
  const float* src; u16* dst; int K, Nn, bx, by;
  if (z < 384){      int i=z/192, r=z%192; src=wqkv+(long)i*196608; dst=wqkvT+(long)i*196608; K=256; Nn=768; bx=r%24; by=r/24; }
  else if (z < 512){ int zz=z-384; int i=zz/64, r=zz%64; src=wout+(long)i*65536; dst=woutT+(long)i*65536; K=256; Nn=256; bx=r%8; by=r/8; }
  else if (z < 768){ int zz=z-512; int i=zz/128, r=zz%128; src=w1+(long)i*131072; dst=w1T+(long)i*131072; K=256; Nn=512; bx=r%16; by=r/16; }
  else {             int zz=z-768; int i=zz/128, r=zz%128; src=w2+(long)i*131072; dst=w2T+(long)i*131072; K=512; Nn=256; bx=r%8; by=r/8; }
  int n0 = bx*32, k0 = by*32;
  int tx = threadIdx.x&31, ty = threadIdx.x>>5;
  #pragma unroll
  for (int i=0;i<4;i++) t[ty+i*8][tx] = src[(long)(k0+ty+i*8)*Nn + n0+tx];
  __syncthreads();
  #pragma unroll
  for (int i=0;i<4;i++) dst[(long)(n0+ty+i*8)*K + k0+tx] = f2bf(t[tx][ty+i*8]);
}

// ---------------------------------------------------------------------------
extern "C" void kernel_launch(void* const* d_in, const int* in_sizes, int n_in,
                              void* d_out, int out_size, void* d_ws, size_t ws_size,
                              hipStream_t stream)
{
  const float* x    = (const float*)d_in[0];
  const float* ln1g = (const float*)d_in[1];
  const float* ln1b = (const float*)d_in[2];
  const float* wqkv = (const float*)d_in[3];
  const float* wout = (const float*)d_in[4];
  const float* bout = (const float*)d_in[5];
  const float* resw = (const float*)d_in[6];
  const float* ln2g = (const float*)d_in[7];
  const float* ln2b = (const float*)d_in[8];
  const float* w1   = (const float*)d_in[9];
  const float* b1   = (const float*)d_in[10];
  const float* w2   = (const float*)d_in[11];
  const float* b2   = (const float*)d_in[12];
  float* y = (float*)d_out;
  char* ws = (char*)d_ws;

  u16* xn    = (u16*)(ws + 0);
  u16* qb    = (u16*)(ws + 8388608);
  u16* kb    = (u16*)(ws + 16777216);
  u16* vb    = (u16*)(ws + 25165824);
  u16* ql    = (u16*)(ws + 33554432);
  u16* kl    = (u16*)(ws + 34078720);
  u16* X     = (u16*)(ws + 34603008);
  u16* XT    = (u16*)(ws + 38797312);     // doubles as z~0
  u16* w3T   = (u16*)(ws + 42991616);     // [32][64][256] bf16 (rows>=32 zero)
  u16* g1T   = (u16*)(ws + 44040192);     // [32][64][256]
  u16* aT    = (u16*)(ws + 45088768);     // [32][64][256]
  u16* bT    = (u16*)(ws + 46137344);     // [32][64][256]
  // pinv work region: 6 x 4 MB
  u16* WA    = (u16*)(ws + 51380224);
  u16* WB    = (u16*)(ws + 55574528);
  u16* Sb    = (u16*)(ws + 59768832);
  u16* Mb    = (u16*)(ws + 63963136);
  u16* zA    = (u16*)(ws + 68157440);
  u16* zB    = (u16*)(ws + 72351744);
  float* num_p = (float*)(ws + 76546048);  // 8 MB
  float* den_p = (float*)(ws + 84934656);
  float* cs_p  = (float*)(ws + 85196800);
  float* scal  = (float*)(ws + 85458944);
  u16* uT    = (u16*)(ws + 85459200);
  u16* aoutb = (u16*)(ws + 85983488);
  u16* wqkvT = (u16*)(ws + 94372096);
  u16* woutT = (u16*)(ws + 95158528);
  u16* w1T   = (u16*)(ws + 95420672);
  u16* w2T   = (u16*)(ws + 95944960);
  u16* hdn   = (u16*)(ws + 51380224);      // overlays pinv region (dead by FFN)

  (void)in_sizes; (void)n_in; (void)out_size; (void)ws_size;

  kcvtall<<<1024,256,0,stream>>>(wqkv, wout, w1, w2, wqkvT, woutT, w1T, w2T);

  for (int i=0;i<2;i++){
    kln<<<4096,256,0,stream>>>(i==0 ? x : y, ln1g + i*256, ln1b + i*256, xn);
    kgemm2<EPI_QKV><<<dim3(128,6),256,0,stream>>>(xn, wqkvT + (long)i*196608, 256, 256, 256,
        nullptr, nullptr, 0, qb,kb,vb, ql,kl);
    kattn23<<<dim3(16,32),256,0,stream>>>(ql, kl, X, XT, cs_p, kb, vb, num_p, den_p);
    ks0w3<<<33,256,0,stream>>>(cs_p, scal, num_p, den_p, w3T);

    // ---- pinv: W' = W@M, z~' = z~@M with M = 0.25(13I - 15W + 7S - S@W) ----
    kpinv<PM_W0><<<dim3(4,4,32),256,0,stream>>>(X, X, nullptr, WA, nullptr,
        nullptr, nullptr, nullptr, scal);
    u16 *Wi = WA, *Wo = WB, *zi = XT, *zo = zA;
    for (int it=0; it<5; it++){
      kpinv<PM_S><<<dim3(4,4,32),256,0,stream>>>(Wi, Wi, nullptr, Sb, nullptr,
          nullptr, nullptr, nullptr, nullptr);
      kpinv<PM_M><<<dim3(4,4,32),256,0,stream>>>(Sb, Wi, nullptr, Mb, nullptr,
          Wi, Sb, nullptr, nullptr);
      kpinv<PM_PAIR><<<dim3(4,4,64),256,0,stream>>>(Wi, Mb, zi, Wo, zo,
          nullptr, nullptr, nullptr, nullptr);
      u16* t = Wi; Wi = Wo; Wo = t;
      zi = zo; zo = (zo == zA) ? zB : zA;
    }
    // thin tail: a=W5@w3, b=W5@a, c=W5@b (g1 = .25(13w3-15a+7b-c)); u=z5@g1*s0
    kpinv<PM_TH><<<dim3(4,1,32),256,0,stream>>>(Wi, w3T, nullptr, aT, nullptr,
        nullptr, nullptr, nullptr, nullptr);
    kpinv<PM_TH><<<dim3(4,1,32),256,0,stream>>>(Wi, aT, nullptr, bT, nullptr,
        nullptr, nullptr, nullptr, nullptr);
    kpinv<PM_THG><<<dim3(4,1,32),256,0,stream>>>(Wi, bT, nullptr, g1T, nullptr,
        w3T, aT, bT, nullptr);
    kpinv<PM_THINU><<<dim3(4,1,32),256,0,stream>>>(zi, g1T, nullptr, uT, nullptr,
        nullptr, nullptr, nullptr, scal);

    kattn1u<<<dim3(32,32),256,0,stream>>>(qb, kl, uT, vb, resw + i*264, aoutb);
    kgemm<EPI_BIAS_RES><<<dim3(128,4),256,0,stream>>>(aoutb, woutT + (long)i*65536, 256,256,256,
        bout + i*256, i==0 ? x : y, y, nullptr, 256);
    kln<<<4096,256,0,stream>>>(y, ln2g + i*256, ln2b + i*256, xn);
    kgemm2<EPI_BIAS_GELU><<<dim3(128,4),256,0,stream>>>(xn, w1T + (long)i*131072, 256, 256, 256,
        b1 + i*512, hdn, 512, nullptr,nullptr,nullptr, nullptr,nullptr);
    kgemm<EPI_BIAS_RES><<<dim3(128,4),256,0,stream>>>(hdn, w2T + (long)i*131072, 512,512,512,
        b2 + i*256, y, y, nullptr, 256);
  }
}

// Round 15
// 711.345 us; speedup vs baseline: 1.0663x; 1.0294x over previous
//
#include <hip/hip_runtime.h>
#include <math.h>

typedef float f32x4 __attribute__((ext_vector_type(4)));
typedef short s16x8 __attribute__((ext_vector_type(8)));
typedef unsigned short u16;

#define MFMA16(a,b,c) __builtin_amdgcn_mfma_f32_16x16x32_bf16((a),(b),(c),0,0,0)

__device__ __forceinline__ float bf2f(u16 u){
  union { unsigned int i; float f; } v; v.i = ((unsigned int)u)<<16; return v.f;
}
__device__ __forceinline__ u16 f2bf(float f){
  union { float f; unsigned int i; } v; v.f = f;
  unsigned int x = v.i;
  return (u16)((x + 0x7fffu + ((x>>16)&1u))>>16);
}

enum { EPI_QKV=0, EPI_PINV=1, EPI_BIAS_RES=2, EPI_BIAS_GELU=3 };

// ---------------------------------------------------------------------------
// kgemm: BM=128, BN=64, BK=32 (for N=256 outputs: RES / RES2)
// ---------------------------------------------------------------------------
template<int EPI>
__global__ __launch_bounds__(256)
void kgemm(const u16* __restrict__ A, const u16* __restrict__ BT, int K, int lda, int ldb,
           const float* __restrict__ bias, const float* __restrict__ base,
           float* __restrict__ resout,
           u16* __restrict__ outb, int ldc)
{
  __shared__ __align__(16) u16 As[128][40];
  __shared__ __align__(16) u16 Bs[64][40];
  const int tid = threadIdx.x;
  const int w = tid>>6, l = tid&63, q = l>>4, ln = l&15;
  const int m0 = blockIdx.x*128, n0 = blockIdx.y*64;

  f32x4 acc[2][4];
  #pragma unroll
  for (int i=0;i<2;i++)
    #pragma unroll
    for (int j=0;j<4;j++){ acc[i][j][0]=0.f; acc[i][j][1]=0.f; acc[i][j][2]=0.f; acc[i][j][3]=0.f; }

  const int arow = tid>>2, aseg = tid&3;
  for (int k0=0; k0<K; k0+=32){
    *(int4*)&As[arow][aseg*8]    = *(const int4*)(A + (long)(m0+arow)*lda + k0 + aseg*8);
    *(int4*)&As[arow+64][aseg*8] = *(const int4*)(A + (long)(m0+arow+64)*lda + k0 + aseg*8);
    *(int4*)&Bs[arow][aseg*8]    = *(const int4*)(BT + (long)(n0+arow)*ldb + k0 + aseg*8);
    __syncthreads();
    s16x8 af[2], bfr[4];
    #pragma unroll
    for (int mt=0;mt<2;mt++) af[mt] = *(const s16x8*)&As[w*32 + mt*16 + ln][q*8];
    #pragma unroll
    for (int nt=0;nt<4;nt++) bfr[nt] = *(const s16x8*)&Bs[nt*16 + ln][q*8];
    #pragma unroll
    for (int mt=0;mt<2;mt++)
      #pragma unroll
      for (int nt=0;nt<4;nt++)
        acc[mt][nt] = MFMA16(af[mt], bfr[nt], acc[mt][nt]);
    __syncthreads();
  }

  #pragma unroll
  for (int mt=0;mt<2;mt++)
  #pragma unroll
  for (int nt=0;nt<4;nt++)
  #pragma unroll
  for (int r=0;r<4;r++){
    int mrow = m0 + w*32 + mt*16 + q*4 + r;
    int ncol = n0 + nt*16 + ln;
    float v = acc[mt][nt][r];
    if (EPI==EPI_BIAS_RES){
      long idx = (long)mrow*ldc + ncol;
      resout[idx] = base[idx] + v + bias[ncol];
    } else {
      outb[(long)mrow*ldc + ncol] = f2bf(v);
    }
  }
}

// ---------------------------------------------------------------------------
// kgemm2: BM=128, BN=128, BK=32, 4x4 frags/wave (2x2 wave grid) — LDS-lean.
// For wide GEMMs: QKV (N=768) and FFN1+GELU (N=512).
// EPI_QKV also emits landmark means.
// ---------------------------------------------------------------------------
template<int EPI>
__global__ __launch_bounds__(256)
void kgemm2(const u16* __restrict__ A, const u16* __restrict__ BT, int K, int lda, int ldb,
            const float* __restrict__ bias, u16* __restrict__ outb, int ldc,
            u16* __restrict__ qo, u16* __restrict__ ko, u16* __restrict__ vo,
            u16* __restrict__ qlm, u16* __restrict__ klm)
{
  __shared__ __align__(16) u16 As[128][40];
  __shared__ __align__(16) u16 Bs[128][40];
  const int tid = threadIdx.x;
  const int w = tid>>6, wy = w>>1, wx = w&1, l = tid&63, q = l>>4, ln = l&15;
  const int m0 = blockIdx.x*128, n0 = blockIdx.y*128;

  f32x4 acc[4][4];
  #pragma unroll
  for (int i=0;i<4;i++)
    #pragma unroll
    for (int j=0;j<4;j++){ acc[i][j][0]=0.f; acc[i][j][1]=0.f; acc[i][j][2]=0.f; acc[i][j][3]=0.f; }

  const int srow = tid>>1, sc = (tid&1)*16;
  for (int k0=0; k0<K; k0+=32){
    *(int4*)&As[srow][sc]   = *(const int4*)(A + (long)(m0+srow)*lda + k0 + sc);
    *(int4*)&As[srow][sc+8] = *(const int4*)(A + (long)(m0+srow)*lda + k0 + sc + 8);
    *(int4*)&Bs[srow][sc]   = *(const int4*)(BT + (long)(n0+srow)*ldb + k0 + sc);
    *(int4*)&Bs[srow][sc+8] = *(const int4*)(BT + (long)(n0+srow)*ldb + k0 + sc + 8);
    __syncthreads();
    s16x8 af[4], bfr[4];
    #pragma unroll
    for (int mt=0;mt<4;mt++) af[mt] = *(const s16x8*)&As[wy*64 + mt*16 + ln][q*8];
    #pragma unroll
    for (int nt=0;nt<4;nt++) bfr[nt] = *(const s16x8*)&Bs[wx*64 + nt*16 + ln][q*8];
    #pragma unroll
    for (int mt=0;mt<4;mt++)
      #pragma unroll
      for (int nt=0;nt<4;nt++)
        acc[mt][nt] = MFMA16(af[mt], bfr[nt], acc[mt][nt]);
    __syncthreads();
  }

  #pragma unroll
  for (int mt=0;mt<4;mt++)
  #pragma unroll
  for (int nt=0;nt<4;nt++){
    int ncol = n0 + wx*64 + nt*16 + ln;
    if (EPI==EPI_QKV){
      int sel = ncol>>8, hd = ncol&255, h = hd>>5, d = hd&31;
      u16* dst = sel==0 ? qo : (sel==1 ? ko : vo);
      float sc2 = (sel==0) ? 0.17677669529663689f : 1.f;   // dh^-0.5 on q
      float s = 0.f;
      #pragma unroll
      for (int r=0;r<4;r++){
        int mrow = m0 + wy*64 + mt*16 + q*4 + r;
        int b = mrow>>12, n = mrow&4095;
        float v = acc[mt][nt][r]*sc2;
        dst[(((long)(b*8+h)*4096 + n)<<5) + d] = f2bf(v);
        s += v;
      }
      if (sel < 2){
        s += __shfl_xor(s, 16);
        s += __shfl_xor(s, 32);
        if (q == 0){
          int mrow0 = m0 + wy*64 + mt*16;
          int b = mrow0>>12, grp = (mrow0&4095)>>4;
          u16* ldst = (sel==0) ? qlm : klm;
          ldst[(((long)(b*8+h)*256 + grp)<<5) + d] = f2bf(s*(1.0f/16.0f));
        }
      }
    } else { // EPI_BIAS_GELU
      #pragma unroll
      for (int r=0;r<4;r++){
        int mrow = m0 + wy*64 + mt*16 + q*4 + r;
        float x = acc[mt][nt][r] + bias[ncol];
        float g = 0.5f*x*(1.0f + erff(x*0.70710678118654752f));
        outb[(long)mrow*ldc + ncol] = f2bf(g);
      }
    }
  }
}

// ---------------------------------------------------------------------------
// Batched pinv GEMM, 256-K per batch, 64x64 tiles, BK=64 (4 barrier pairs).
// LDS 2x[64][72]=18.4 KB -> still 8 WG/CU (thread-slot bound, same as BK=32).
//  PM_W0/S/M/PAIR: square modes, grids (4,4,32)/(4,4,64)
//  PM_TH  : outT = (A@B)^T        grid (4,1,32), B stride 16384
//  PM_THG : PM_TH + g1 epilogue: g1T = .25(13*w3T-15*aT+7*bT-cT)
//  PM_THINU: uT = (A@B)^T * s0, cols<32
// ---------------------------------------------------------------------------
enum { PM_W0=0, PM_S=1, PM_M=2, PM_PAIR=3, PM_TH=4, PM_THG=5, PM_THINU=6 };

template<int MODE>
__global__ __launch_bounds__(256)
void kpinv(const u16* __restrict__ A, const u16* __restrict__ B,
           const u16* __restrict__ A2,
           u16* __restrict__ out, u16* __restrict__ out2,
           const u16* __restrict__ Wp, const u16* __restrict__ Sp,
           const u16* __restrict__ Tp,
           const float* __restrict__ sptr)
{
  __shared__ __align__(16) u16 As[64][72];
  __shared__ __align__(16) u16 Bs[64][72];
  const int tid=threadIdx.x, w=tid>>6, l=tid&63, q=l>>4, ln=l&15;
  int bz = blockIdx.z, half = 0;
  if (MODE==PM_PAIR){ half = bz>>5; bz &= 31; }
  const u16* Ap = ((MODE==PM_PAIR && half) ? A2 : A) + (long)bz*65536;
  const long bstr = (MODE>=PM_TH) ? 16384 : 65536;
  const u16* Bp = B + (long)bz*bstr;
  const int m0 = blockIdx.x*64, n0 = blockIdx.y*64;
  float bscale = (MODE==PM_W0) ? *sptr : 1.f;

  f32x4 acc[4];
  #pragma unroll
  for (int j=0;j<4;j++){ acc[j][0]=0.f; acc[j][1]=0.f; acc[j][2]=0.f; acc[j][3]=0.f; }

  const int srow = tid>>2, scol = (tid&3)*16;
  for (int k0=0;k0<256;k0+=64){
    *(int4*)&As[srow][scol]   = *(const int4*)(Ap + (long)(m0+srow)*256 + k0 + scol);
    *(int4*)&As[srow][scol+8] = *(const int4*)(Ap + (long)(m0+srow)*256 + k0 + scol + 8);
    if (MODE==PM_W0){
      #pragma unroll
      for (int s=0;s<2;s++){
        int4 raw = *(const int4*)(Bp + (long)(n0+srow)*256 + k0 + scol + s*8);
        u16* pr = (u16*)&raw; u16 o[8];
        #pragma unroll
        for (int j=0;j<8;j++) o[j] = f2bf(bscale*bf2f(pr[j]));
        *(int4*)&Bs[srow][scol + s*8] = *(int4*)o;
      }
    } else {
      *(int4*)&Bs[srow][scol]   = *(const int4*)(Bp + (long)(n0+srow)*256 + k0 + scol);
      *(int4*)&Bs[srow][scol+8] = *(const int4*)(Bp + (long)(n0+srow)*256 + k0 + scol + 8);
    }
    __syncthreads();
    #pragma unroll
    for (int kb=0;kb<2;kb++){
      s16x8 af = *(const s16x8*)&As[w*16 + ln][kb*32 + q*8];
      #pragma unroll
      for (int nt=0;nt<4;nt++){
        s16x8 bfr = *(const s16x8*)&Bs[nt*16 + ln][kb*32 + q*8];
        acc[nt] = MFMA16(af, bfr, acc[nt]);
      }
    }
    __syncthreads();
  }

  #pragma unroll
  for (int nt=0;nt<4;nt++)
  #pragma unroll
  for (int r=0;r<4;r++){
    int mrow = m0 + w*16 + q*4 + r;
    int ncol = n0 + nt*16 + ln;
    float v = acc[nt][r];
    long idx  = (long)bz*65536 + (long)mrow*256 + ncol;
    long idxt = (long)bz*16384 + (long)ncol*256 + mrow;
    if (MODE==PM_M){
      float wv = bf2f(Wp[idx]), sv = bf2f(Sp[idx]);
      float m = 0.25f*(((mrow==ncol)?13.f:0.f) - 15.f*wv + 7.f*sv - v);
      out[idx] = f2bf(m);
    } else if (MODE==PM_PAIR){
      (half ? out2 : out)[idx] = f2bf(v);
    } else if (MODE==PM_TH){
      out[idxt] = f2bf(v);
    } else if (MODE==PM_THG){
      float g = 0.25f*(13.f*bf2f(Wp[idxt]) - 15.f*bf2f(Sp[idxt]) + 7.f*bf2f(Tp[idxt]) - v);
      out[idxt] = f2bf(g);
    } else if (MODE==PM_THINU){
      if (ncol < 32) out[(long)bz*8192 + (long)ncol*256 + mrow] = f2bf(v*(*sptr));
    } else { // W0, S
      out[idx] = f2bf(v);
    }
  }
}

// ---------------------------------------------------------------------------
// LayerNorm: one wave per row (256 cols), write bf16
// ---------------------------------------------------------------------------
__global__ __launch_bounds__(256)
void kln(const float* __restrict__ y, const float* __restrict__ g, const float* __restrict__ b,
         u16* __restrict__ out)
{
  int w = threadIdx.x>>6, l = threadIdx.x&63;
  long row = (long)blockIdx.x*4 + w;
  float4 v = ((const float4*)(y + row*256))[l];
  float s = v.x+v.y+v.z+v.w;
  #pragma unroll
  for (int m=1;m<64;m<<=1) s += __shfl_xor(s, m);
  float mu = s*(1.0f/256.0f);
  float dx=v.x-mu, dy=v.y-mu, dz=v.z-mu, dw=v.w-mu;
  float s2 = dx*dx+dy*dy+dz*dz+dw*dw;
  #pragma unroll
  for (int m=1;m<64;m<<=1) s2 += __shfl_xor(s2, m);
  float rs = rsqrtf(s2*(1.0f/256.0f) + 1e-5f);
  float4 gg = ((const float4*)g)[l];
  float4 bb = ((const float4*)b)[l];
  ushort4 o;
  o.x = f2bf(dx*rs*gg.x + bb.x);
  o.y = f2bf(dy*rs*gg.y + bb.y);
  o.z = f2bf(dz*rs*gg.z + bb.z);
  o.w = f2bf(dw*rs*gg.w + bb.w);
  *(ushort4*)(out + row*256 + l*4) = o;
}

// ---------------------------------------------------------------------------
// Merged attn2 + attn3v (independent; grid (16,32): x<8 attn2, x>=8 attn3v)
// ---------------------------------------------------------------------------
__global__ __launch_bounds__(256)
void kattn23(const u16* __restrict__ ql, const u16* __restrict__ kl,
             u16* __restrict__ X, u16* __restrict__ XT, float* __restrict__ cs_p,
             const u16* __restrict__ kk, const u16* __restrict__ vv,
             float* __restrict__ num_p, float* __restrict__ den_p)
{
  __shared__ __align__(16) u16 Pbuf[4][64][40];
  __shared__ __align__(16) u16 vT[32][40];
  __shared__ float qrow[32][33];
  __shared__ float psum[32][4];
  __shared__ float rsum[32];
  int bh = blockIdx.y;
  int tid = threadIdx.x, w = tid>>6, l = tid&63, q = l>>4, ln = l&15;

  if (blockIdx.x < 8){
    int r0 = blockIdx.x*32;
    int c = tid;
    #pragma unroll
    for (int i=0;i<4;i++){
      int e = c*4+i; int rr = e>>5, dd = e&31;
      qrow[rr][dd] = bf2f(ql[((long)bh*256 + r0+rr)*32 + dd]);
    }
    float kc[32];
    {
      const u16* kp = kl + ((long)bh*256 + c)*32;
      #pragma unroll
      for (int d=0;d<32;d++) kc[d] = bf2f(kp[d]);
    }
    __syncthreads();
    float er[32]; float colacc = 0.f;
    for (int r=0;r<32;r++){
      float s = 0.f;
      #pragma unroll
      for (int d=0;d<32;d++) s += qrow[r][d]*kc[d];
      float e = __expf(s);
      er[r] = e;
      float wsum = e;
      #pragma unroll
      for (int m=1;m<64;m<<=1) wsum += __shfl_xor(wsum, m);
      if (l==0) psum[r][w] = wsum;
    }
    __syncthreads();
    if (c<32) rsum[c] = psum[c][0]+psum[c][1]+psum[c][2]+psum[c][3];
    __syncthreads();
    for (int r=0;r<32;r++){
      float x = er[r]/rsum[r];
      u16 xb = f2bf(x);
      X [((long)bh*256 + r0+r)*256 + c] = xb;
      XT[((long)bh*256 + c)*256 + r0+r] = xb;
      colacc += x;
    }
    cs_p[(long)blockIdx.x*8192 + bh*256 + c] = colacc;
    return;
  }

  int chunk = blockIdx.x - 8;
  f32x4 z4; z4[0]=0.f; z4[1]=0.f; z4[2]=0.f; z4[3]=0.f;
  f32x4 acc[4][2]; f32x4 dacc[4];
  #pragma unroll
  for (int mt=0;mt<4;mt++){ dacc[mt]=z4; acc[mt][0]=z4; acc[mt][1]=z4; }
  const u16* qlb = ql + (long)bh*8192;
  const u16* kb  = kk + (long)bh*131072;
  const u16* vb  = vv + (long)bh*131072;
  int vn = tid>>3, vd = (tid&7)*4;
  for (int s=0;s<16;s++){
    int n0 = chunk*512 + s*32;
    ushort4 vx = *(const ushort4*)(vb + (long)(n0+vn)*32 + vd);
    vT[vd+0][vn]=vx.x; vT[vd+1][vn]=vx.y; vT[vd+2][vn]=vx.z; vT[vd+3][vn]=vx.w;
    __syncthreads();
    s16x8 bk[2];
    #pragma unroll
    for (int nt=0;nt<2;nt++) bk[nt] = *(const s16x8*)(kb + (long)(n0 + nt*16 + ln)*32 + q*8);
    #pragma unroll
    for (int mt=0;mt<4;mt++){
      s16x8 aq = *(const s16x8*)(qlb + (long)(w*64 + mt*16 + ln)*32 + q*8);
      #pragma unroll
      for (int nt=0;nt<2;nt++){
        f32x4 sf = MFMA16(aq, bk[nt], z4);
        f32x4 ef;
        #pragma unroll
        for (int r=0;r<4;r++) ef[r] = __expf(sf[r]);
        dacc[mt] += ef;
        #pragma unroll
        for (int r=0;r<4;r++) Pbuf[w][mt*16 + q*4 + r][nt*16 + ln] = f2bf(ef[r]);
      }
    }
    #pragma unroll
    for (int mt=0;mt<4;mt++){
      s16x8 ap = *(const s16x8*)&Pbuf[w][mt*16 + ln][q*8];
      #pragma unroll
      for (int nt=0;nt<2;nt++){
        s16x8 bv = *(const s16x8*)&vT[nt*16 + ln][q*8];
        acc[mt][nt] = MFMA16(ap, bv, acc[mt][nt]);
      }
    }
    __syncthreads();
  }
  #pragma unroll
  for (int mt=0;mt<4;mt++)
    #pragma unroll
    for (int r=0;r<4;r++){
      float x = dacc[mt][r];
      x += __shfl_xor(x,1); x += __shfl_xor(x,2); x += __shfl_xor(x,4); x += __shfl_xor(x,8);
      dacc[mt][r] = x;
    }
  long pbase = (long)(chunk*32 + bh);
  #pragma unroll
  for (int mt=0;mt<4;mt++)
    #pragma unroll
    for (int nt=0;nt<2;nt++)
      #pragma unroll
      for (int r=0;r<4;r++){
        int mg = w*64 + mt*16 + q*4 + r;
        num_p[pbase*8192 + (long)mg*32 + nt*16 + ln] = acc[mt][nt][r];
      }
  if (ln==0){
    #pragma unroll
    for (int mt=0;mt<4;mt++)
      #pragma unroll
      for (int r=0;r<4;r++)
        den_p[pbase*256 + w*64 + mt*16 + q*4 + r] = dacc[mt][r];
  }
}

// ---------------------------------------------------------------------------
// ks0w3: WG0 = 1/max colsum; WG 1+bh = w3T prep (coalesced + LDS transpose)
// ---------------------------------------------------------------------------
__global__ __launch_bounds__(256)
void ks0w3(const float* __restrict__ cs_p, float* __restrict__ scal,
           const float* __restrict__ num_p, const float* __restrict__ den_p,
           u16* __restrict__ w3T)
{
  int t = threadIdx.x;
  if (blockIdx.x == 0){
    __shared__ float red[256];
    float m = 0.f;
    for (int i=t;i<8192;i+=256){
      float s = 0.f;
      #pragma unroll
      for (int c=0;c<8;c++) s += cs_p[(long)c*8192 + i];
      m = fmaxf(m, s);
    }
    red[t] = m; __syncthreads();
    for (int s=128;s>0;s>>=1){ if (t<s) red[t] = fmaxf(red[t], red[t+s]); __syncthreads(); }
    if (t==0) scal[0] = 1.0f/red[0];
    return;
  }
  int bh = blockIdx.x - 1;
  __shared__ float lt[32][257];
  for (int i=t;i<8192;i+=256){
    int m = i>>5, d = i&31;
    float sn = 0.f, sd = 0.f;
    #pragma unroll
    for (int c=0;c<8;c++){
      sn += num_p[((long)(c*32+bh))*8192 + i];
      sd += den_p[(c*32+bh)*256 + m];
    }
    lt[d][m] = sn/sd;
  }
  __syncthreads();
  u16* o = w3T + (long)bh*16384;
  for (int j=t;j<16384;j+=256){
    int d = j>>8, m = j&255;
    o[j] = (d<32) ? f2bf(lt[d][m]) : (u16)0;
  }
}

// ---------------------------------------------------------------------------
// attn1 fused + depthwise residual conv:
// aoutb = softmax(q @ k_l^T) @ u + conv33(v)
// ---------------------------------------------------------------------------
__global__ __launch_bounds__(256)
void kattn1u(const u16* __restrict__ qq, const u16* __restrict__ kl, const u16* __restrict__ uT,
             const u16* __restrict__ vv, const float* __restrict__ rw,
             u16* __restrict__ aoutb)
{
  int nch = blockIdx.x, bh = blockIdx.y;
  int b = bh>>3, h = bh&7;
  int tid = threadIdx.x, w = tid>>6, l = tid&63, q = l>>4, ln = l&15;
  __shared__ __align__(16) u16 Pbuf[4][32][40];
  __shared__ __align__(16) u16 vtile[160][36];
  int r0g = nch*128;
  const u16* vb = vv + (long)bh*131072;
  #pragma unroll
  for (int it=0; it<5; it++){
    int slot = tid + it*256;
    int rr = slot>>3, c = (slot&7)*4;
    int s = r0g - 16 + rr;
    ushort4 val; val.x=0; val.y=0; val.z=0; val.w=0;
    if (s>=0 && s<4096) val = *(const ushort4*)(vb + (long)s*32 + c);
    *(ushort4*)&vtile[rr][c] = val;
  }
  __syncthreads();

  f32x4 z4; z4[0]=0.f; z4[1]=0.f; z4[2]=0.f; z4[3]=0.f;
  f32x4 acc[2][2]; f32x4 dacc[2];
  #pragma unroll
  for (int mt=0;mt<2;mt++){ dacc[mt]=z4; acc[mt][0]=z4; acc[mt][1]=z4; }
  const u16* qb  = qq + (long)bh*131072;
  const u16* klb = kl + (long)bh*8192;
  const u16* ub  = uT + (long)bh*8192;
  int r0 = r0g + w*32;
  for (int s=0;s<8;s++){
    s16x8 bk[2];
    #pragma unroll
    for (int nt=0;nt<2;nt++) bk[nt] = *(const s16x8*)(klb + (long)(s*32 + nt*16 + ln)*32 + q*8);
    #pragma unroll
    for (int mt=0;mt<2;mt++){
      s16x8 aq = *(const s16x8*)(qb + (long)(r0 + mt*16 + ln)*32 + q*8);
      #pragma unroll
      for (int nt=0;nt<2;nt++){
        f32x4 sf = MFMA16(aq, bk[nt], z4);
        f32x4 ef;
        #pragma unroll
        for (int r=0;r<4;r++) ef[r] = __expf(sf[r]);
        dacc[mt] += ef;
        #pragma unroll
        for (int r=0;r<4;r++) Pbuf[w][mt*16 + q*4 + r][nt*16 + ln] = f2bf(ef[r]);
      }
    }
    #pragma unroll
    for (int mt=0;mt<2;mt++){
      s16x8 ap = *(const s16x8*)&Pbuf[w][mt*16 + ln][q*8];
      #pragma unroll
      for (int nt=0;nt<2;nt++){
        s16x8 bu = *(const s16x8*)(ub + (long)(nt*16 + ln)*256 + s*32 + q*8);
        acc[mt][nt] = MFMA16(ap, bu, acc[mt][nt]);
      }
    }
  }
  #pragma unroll
  for (int mt=0;mt<2;mt++)
    #pragma unroll
    for (int r=0;r<4;r++){
      float x = dacc[mt][r];
      x += __shfl_xor(x,1); x += __shfl_xor(x,2); x += __shfl_xor(x,4); x += __shfl_xor(x,8);
      dacc[mt][r] = x;
    }

  const float* wp = rw + h*33;
  float w_[33];
  #pragma unroll
  for (int j=0;j<33;j++) w_[j] = wp[j];

  #pragma unroll
  for (int mt=0;mt<2;mt++){
    int nl = w*32 + mt*16 + q*4;
    #pragma unroll
    for (int nt=0;nt<2;nt++){
      int d = nt*16 + ln;
      float vvv[36];
      #pragma unroll
      for (int j=0;j<36;j++) vvv[j] = bf2f(vtile[nl + j][d]);
      #pragma unroll
      for (int r=0;r<4;r++){
        float cv = 0.f;
        #pragma unroll
        for (int j=0;j<33;j++) cv += w_[j]*vvv[r+j];
        int n = r0 + mt*16 + q*4 + r;
        long oidx = ((long)b*4096 + n)*256 + h*32 + d;
        aoutb[oidx] = f2bf(acc[mt][nt][r]/dacc[mt][r] + cv);
      }
    }
  }
}

// ---------------------------------------------------------------------------
// Merged weight transpose+cast: all 4 weights in one launch (grid 1024).
// ---------------------------------------------------------------------------
__global__ __launch_bounds__(256)
void kcvtall(const float* __restrict__ wqkv, const float* __restrict__ wout,
             const float* __restrict__ w1, const float* __restrict__ w2,
             u16* __restrict__ wqkvT, u16* __restrict__ woutT,
             u16* __restrict__ w1T, u16* __restrict__ w2T)
{
  __shared__ float t[32][33];
  int z = blockIdx.x;
  const float* src; u16* dst; int K, Nn, bx, by;
  if (z < 384){      int i=z/192, r=z%192; src=wqkv+(long)i*196608; dst=wqkvT+(long)i*196608; K=256; Nn=768; bx=r%24; by=r/24; }
  else if (z < 512){ int zz=z-384; int i=zz/64, r=zz%64; src=wout+(long)i*65536; dst=woutT+(long)i*65536; K=256; Nn=256; bx=r%8; by=r/8; }
  else if (z < 768){ int zz=z-512; int i=zz/128, r=zz%128; src=w1+(long)i*131072; dst=w1T+(long)i*131072; K=256; Nn=512; bx=r%16; by=r/16; }
  else {             int zz=z-768; int i=zz/128, r=zz%128; src=w2+(long)i*131072; dst=w2T+(long)i*131072; K=512; Nn=256; bx=r%8; by=r/8; }
  int n0 = bx*32, k0 = by*32;
  int tx = threadIdx.x&31, ty = threadIdx.x>>5;
  #pragma unroll
  for (int i=0;i<4;i++) t[ty+i*8][tx] = src[(long)(k0+ty+i*8)*Nn + n0+tx];
  __syncthreads();
  #pragma unroll
  for (int i=0;i<4;i++) dst[(long)(n0+ty+i*8)*K + k0+tx] = f2bf(t[tx][ty+i*8]);
}

// ---------------------------------------------------------------------------
extern "C" void kernel_launch(void* const* d_in, const int* in_sizes, int n_in,
                              void* d_out, int out_size, void* d_ws, size_t ws_size,
                              hipStream_t stream)
{
  const float* x    = (const float*)d_in[0];
  const float* ln1g = (const float*)d_in[1];
  const float* ln1b = (const float*)d_in[2];
  const float* wqkv = (const float*)d_in[3];
  const float* wout = (const float*)d_in[4];
  const float* bout = (const float*)d_in[5];
  const float* resw = (const float*)d_in[6];
  const float* ln2g = (const float*)d_in[7];
  const float* ln2b = (const float*)d_in[8];
  const float* w1   = (const float*)d_in[9];
  const float* b1   = (const float*)d_in[10];
  const float* w2   = (const float*)d_in[11];
  const float* b2   = (const float*)d_in[12];
  float* y = (float*)d_out;
  char* ws = (char*)d_ws;

  u16* xn    = (u16*)(ws + 0);
  u16* qb    = (u16*)(ws + 8388608);
  u16* kb    = (u16*)(ws + 16777216);
  u16* vb    = (u16*)(ws + 25165824);
  u16* ql    = (u16*)(ws + 33554432);
  u16* kl    = (u16*)(ws + 34078720);
  u16* X     = (u16*)(ws + 34603008);
  u16* XT    = (u16*)(ws + 38797312);     // doubles as z~0
  u16* w3T   = (u16*)(ws + 42991616);     // [32][64][256] bf16 (rows>=32 zero)
  u16* g1T   = (u16*)(ws + 44040192);     // [32][64][256]
  u16* aT    = (u16*)(ws + 45088768);     // [32][64][256]
  u16* bT    = (u16*)(ws + 46137344);     // [32][64][256]
  // pinv work region: 6 x 4 MB
  u16* WA    = (u16*)(ws + 51380224);
  u16* WB    = (u16*)(ws + 55574528);
  u16* Sb    = (u16*)(ws + 59768832);
  u16* Mb    = (u16*)(ws + 63963136);
  u16* zA    = (u16*)(ws + 68157440);
  u16* zB    = (u16*)(ws + 72351744);
  float* num_p = (float*)(ws + 76546048);  // 8 MB
  float* den_p = (float*)(ws + 84934656);
  float* cs_p  = (float*)(ws + 85196800);
  float* scal  = (float*)(ws + 85458944);
  u16* uT    = (u16*)(ws + 85459200);
  u16* aoutb = (u16*)(ws + 85983488);
  u16* wqkvT = (u16*)(ws + 94372096);
  u16* woutT = (u16*)(ws + 95158528);
  u16* w1T   = (u16*)(ws + 95420672);
  u16* w2T   = (u16*)(ws + 95944960);
  u16* hdn   = (u16*)(ws + 51380224);      // overlays pinv region (dead by FFN)

  (void)in_sizes; (void)n_in; (void)out_size; (void)ws_size;

  kcvtall<<<1024,256,0,stream>>>(wqkv, wout, w1, w2, wqkvT, woutT, w1T, w2T);

  for (int i=0;i<2;i++){
    kln<<<4096,256,0,stream>>>(i==0 ? x : y, ln1g + i*256, ln1b + i*256, xn);
    kgemm2<EPI_QKV><<<dim3(128,6),256,0,stream>>>(xn, wqkvT + (long)i*196608, 256, 256, 256,
        nullptr, nullptr, 0, qb,kb,vb, ql,kl);
    kattn23<<<dim3(16,32),256,0,stream>>>(ql, kl, X, XT, cs_p, kb, vb, num_p, den_p);
    ks0w3<<<33,256,0,stream>>>(cs_p, scal, num_p, den_p, w3T);

    // ---- pinv: W' = W@M, z~' = z~@M with M = 0.25(13I - 15W + 7S - S@W) ----
    kpinv<PM_W0><<<dim3(4,4,32),256,0,stream>>>(X, X, nullptr, WA, nullptr,
        nullptr, nullptr, nullptr, scal);
    u16 *Wi = WA, *Wo = WB, *zi = XT, *zo = zA;
    for (int it=0; it<5; it++){
      kpinv<PM_S><<<dim3(4,4,32),256,0,stream>>>(Wi, Wi, nullptr, Sb, nullptr,
          nullptr, nullptr, nullptr, nullptr);
      kpinv<PM_M><<<dim3(4,4,32),256,0,stream>>>(Sb, Wi, nullptr, Mb, nullptr,
          Wi, Sb, nullptr, nullptr);
      kpinv<PM_PAIR><<<dim3(4,4,64),256,0,stream>>>(Wi, Mb, zi, Wo, zo,
          nullptr, nullptr, nullptr, nullptr);
      u16* t = Wi; Wi = Wo; Wo = t;
      zi = zo; zo = (zo == zA) ? zB : zA;
    }
    // thin tail: a=W5@w3, b=W5@a, c=W5@b (g1 = .25(13w3-15a+7b-c)); u=z5@g1*s0
    kpinv<PM_TH><<<dim3(4,1,32),256,0,stream>>>(Wi, w3T, nullptr, aT, nullptr,
        nullptr, nullptr, nullptr, nullptr);
    kpinv<PM_TH><<<dim3(4,1,32),256,0,stream>>>(Wi, aT, nullptr, bT, nullptr,
        nullptr, nullptr, nullptr, nullptr);
    kpinv<PM_THG><<<dim3(4,1,32),256,0,stream>>>(Wi, bT, nullptr, g1T, nullptr,
        w3T, aT, bT, nullptr);
    kpinv<PM_THINU><<<dim3(4,1,32),256,0,stream>>>(zi, g1T, nullptr, uT, nullptr,
        nullptr, nullptr, nullptr, scal);

    kattn1u<<<dim3(32,32),256,0,stream>>>(qb, kl, uT, vb, resw + i*264, aoutb);
    kgemm<EPI_BIAS_RES><<<dim3(128,4),256,0,stream>>>(aoutb, woutT + (long)i*65536, 256,256,256,
        bout + i*256, i==0 ? x : y, y, nullptr, 256);
    kln<<<4096,256,0,stream>>>(y, ln2g + i*256, ln2b + i*256, xn);
    kgemm2<EPI_BIAS_GELU><<<dim3(128,4),256,0,stream>>>(xn, w1T + (long)i*131072, 256, 256, 256,
        b1 + i*512, hdn, 512, nullptr,nullptr,nullptr, nullptr,nullptr);
    kgemm<EPI_BIAS_RES><<<dim3(128,4),256,0,stream>>>(hdn, w2T + (long)i*131072, 512,512,512,
        b2 + i*256, y, y, nullptr, 256);
  }
}

// Round 16
// 707.985 us; speedup vs baseline: 1.0714x; 1.0047x over previous
//
#include <hip/hip_runtime.h>
#include <math.h>

typedef float f32x4 __attribute__((ext_vector_type(4)));
typedef short s16x8 __attribute__((ext_vector_type(8)));
typedef unsigned short u16;
typedef unsigned int u32;

#define MFMA16(a,b,c) __builtin_amdgcn_mfma_f32_16x16x32_bf16((a),(b),(c),0,0,0)
#define AS1 __attribute__((address_space(1)))
#define AS3 __attribute__((address_space(3)))

__device__ __forceinline__ void dma16(const u16* g, u16* l){
  __builtin_amdgcn_global_load_lds((const AS1 u32*)g, (AS3 u32*)l, 16, 0, 0);
}

__device__ __forceinline__ float bf2f(u16 u){
  union { unsigned int i; float f; } v; v.i = ((unsigned int)u)<<16; return v.f;
}
__device__ __forceinline__ u16 f2bf(float f){
  union { float f; unsigned int i; } v; v.f = f;
  unsigned int x = v.i;
  return (u16)((x + 0x7fffu + ((x>>16)&1u))>>16);
}

enum { EPI_QKV=0, EPI_PINV=1, EPI_BIAS_RES=2, EPI_BIAS_GELU=3 };

// ---------------------------------------------------------------------------
// kgemm: BM=128, BN=64, BK=32 (N=256 outputs: RES / RES2).
// global_load_lds DMA staging, unpadded LDS + chunk-XOR swizzle
// (slot (row,c) holds global chunk c^((row>>1)&3) -> 2-way-free b128 reads).
// ---------------------------------------------------------------------------
template<int EPI>
__global__ __launch_bounds__(256)
void kgemm(const u16* __restrict__ A, const u16* __restrict__ BT, int K, int lda, int ldb,
           const float* __restrict__ bias, const float* __restrict__ base,
           float* __restrict__ resout,
           u16* __restrict__ outb, int ldc)
{
  __shared__ __align__(16) u16 As[128*32];
  __shared__ __align__(16) u16 Bs[64*32];
  const int tid = threadIdx.x;
  const int w = tid>>6, l = tid&63, q = l>>4, ln = l&15;
  const int m0 = blockIdx.x*128, n0 = blockIdx.y*64;
  const int lrow = l>>2, lch = l&3;

  f32x4 acc[2][4];
  #pragma unroll
  for (int i=0;i<2;i++)
    #pragma unroll
    for (int j=0;j<4;j++){ acc[i][j][0]=0.f; acc[i][j][1]=0.f; acc[i][j][2]=0.f; acc[i][j][3]=0.f; }

  for (int k0=0; k0<K; k0+=32){
    #pragma unroll
    for (int c=0;c<2;c++){
      int row = 32*w + 16*c + lrow;
      int gch = lch ^ ((row>>1)&3);
      dma16(A + (long)(m0+row)*lda + k0 + gch*8, &As[(32*w+16*c)*32]);
    }
    {
      int row = 16*w + lrow;
      int gch = lch ^ ((row>>1)&3);
      dma16(BT + (long)(n0+row)*ldb + k0 + gch*8, &Bs[(16*w)*32]);
    }
    __syncthreads();
    s16x8 af[2], bfr[4];
    #pragma unroll
    for (int mt=0;mt<2;mt++){
      int row = w*32 + mt*16 + ln;
      af[mt] = *(const s16x8*)&As[row*32 + ((q ^ ((row>>1)&3))<<3)];
    }
    #pragma unroll
    for (int nt=0;nt<4;nt++){
      int row = nt*16 + ln;
      bfr[nt] = *(const s16x8*)&Bs[row*32 + ((q ^ ((row>>1)&3))<<3)];
    }
    #pragma unroll
    for (int mt=0;mt<2;mt++)
      #pragma unroll
      for (int nt=0;nt<4;nt++)
        acc[mt][nt] = MFMA16(af[mt], bfr[nt], acc[mt][nt]);
    __syncthreads();
  }

  #pragma unroll
  for (int mt=0;mt<2;mt++)
  #pragma unroll
  for (int nt=0;nt<4;nt++)
  #pragma unroll
  for (int r=0;r<4;r++){
    int mrow = m0 + w*32 + mt*16 + q*4 + r;
    int ncol = n0 + nt*16 + ln;
    float v = acc[mt][nt][r];
    if (EPI==EPI_BIAS_RES){
      long idx = (long)mrow*ldc + ncol;
      resout[idx] = base[idx] + v + bias[ncol];
    } else {
      outb[(long)mrow*ldc + ncol] = f2bf(v);
    }
  }
}

// ---------------------------------------------------------------------------
// kgemm2: BM=128, BN=128, BK=32, 4x4 frags/wave; DMA staging + swizzle.
// For wide GEMMs: QKV (N=768, emits landmark means) and FFN1+GELU (N=512).
// ---------------------------------------------------------------------------
template<int EPI>
__global__ __launch_bounds__(256)
void kgemm2(const u16* __restrict__ A, const u16* __restrict__ BT, int K, int lda, int ldb,
            const float* __restrict__ bias, u16* __restrict__ outb, int ldc,
            u16* __restrict__ qo, u16* __restrict__ ko, u16* __restrict__ vo,
            u16* __restrict__ qlm, u16* __restrict__ klm)
{
  __shared__ __align__(16) u16 As[128*32];
  __shared__ __align__(16) u16 Bs[128*32];
  const int tid = threadIdx.x;
  const int w = tid>>6, wy = w>>1, wx = w&1, l = tid&63, q = l>>4, ln = l&15;
  const int m0 = blockIdx.x*128, n0 = blockIdx.y*128;
  const int lrow = l>>2, lch = l&3;

  f32x4 acc[4][4];
  #pragma unroll
  for (int i=0;i<4;i++)
    #pragma unroll
    for (int j=0;j<4;j++){ acc[i][j][0]=0.f; acc[i][j][1]=0.f; acc[i][j][2]=0.f; acc[i][j][3]=0.f; }

  for (int k0=0; k0<K; k0+=32){
    #pragma unroll
    for (int c=0;c<2;c++){
      int row = 32*w + 16*c + lrow;
      int gch = lch ^ ((row>>1)&3);
      dma16(A + (long)(m0+row)*lda + k0 + gch*8, &As[(32*w+16*c)*32]);
      dma16(BT + (long)(n0+row)*ldb + k0 + gch*8, &Bs[(32*w+16*c)*32]);
    }
    __syncthreads();
    s16x8 af[4], bfr[4];
    #pragma unroll
    for (int mt=0;mt<4;mt++){
      int row = wy*64 + mt*16 + ln;
      af[mt] = *(const s16x8*)&As[row*32 + ((q ^ ((row>>1)&3))<<3)];
    }
    #pragma unroll
    for (int nt=0;nt<4;nt++){
      int row = wx*64 + nt*16 + ln;
      bfr[nt] = *(const s16x8*)&Bs[row*32 + ((q ^ ((row>>1)&3))<<3)];
    }
    #pragma unroll
    for (int mt=0;mt<4;mt++)
      #pragma unroll
      for (int nt=0;nt<4;nt++)
        acc[mt][nt] = MFMA16(af[mt], bfr[nt], acc[mt][nt]);
    __syncthreads();
  }

  #pragma unroll
  for (int mt=0;mt<4;mt++)
  #pragma unroll
  for (int nt=0;nt<4;nt++){
    int ncol = n0 + wx*64 + nt*16 + ln;
    if (EPI==EPI_QKV){
      int sel = ncol>>8, hd = ncol&255, h = hd>>5, d = hd&31;
      u16* dst = sel==0 ? qo : (sel==1 ? ko : vo);
      float sc2 = (sel==0) ? 0.17677669529663689f : 1.f;   // dh^-0.5 on q
      float s = 0.f;
      #pragma unroll
      for (int r=0;r<4;r++){
        int mrow = m0 + wy*64 + mt*16 + q*4 + r;
        int b = mrow>>12, n = mrow&4095;
        float v = acc[mt][nt][r]*sc2;
        dst[(((long)(b*8+h)*4096 + n)<<5) + d] = f2bf(v);
        s += v;
      }
      if (sel < 2){
        s += __shfl_xor(s, 16);
        s += __shfl_xor(s, 32);
        if (q == 0){
          int mrow0 = m0 + wy*64 + mt*16;
          int b = mrow0>>12, grp = (mrow0&4095)>>4;
          u16* ldst = (sel==0) ? qlm : klm;
          ldst[(((long)(b*8+h)*256 + grp)<<5) + d] = f2bf(s*(1.0f/16.0f));
        }
      }
    } else { // EPI_BIAS_GELU
      #pragma unroll
      for (int r=0;r<4;r++){
        int mrow = m0 + wy*64 + mt*16 + q*4 + r;
        float x = acc[mt][nt][r] + bias[ncol];
        float g = 0.5f*x*(1.0f + erff(x*0.70710678118654752f));
        outb[(long)mrow*ldc + ncol] = f2bf(g);
      }
    }
  }
}

// ---------------------------------------------------------------------------
// Batched pinv GEMM, 256-K per batch, 64x64 tiles, BK=64 (proven round-15).
// ---------------------------------------------------------------------------
enum { PM_W0=0, PM_S=1, PM_M=2, PM_PAIR=3, PM_TH=4, PM_THG=5, PM_THINU=6 };

template<int MODE>
__global__ __launch_bounds__(256)
void kpinv(const u16* __restrict__ A, const u16* __restrict__ B,
           const u16* __restrict__ A2,
           u16* __restrict__ out, u16* __restrict__ out2,
           const u16* __restrict__ Wp, const u16* __restrict__ Sp,
           const u16* __restrict__ Tp,
           const float* __restrict__ sptr)
{
  __shared__ __align__(16) u16 As[64][72];
  __shared__ __align__(16) u16 Bs[64][72];
  const int tid=threadIdx.x, w=tid>>6, l=tid&63, q=l>>4, ln=l&15;
  int bz = blockIdx.z, half = 0;
  if (MODE==PM_PAIR){ half = bz>>5; bz &= 31; }
  const u16* Ap = ((MODE==PM_PAIR && half) ? A2 : A) + (long)bz*65536;
  const long bstr = (MODE>=PM_TH) ? 16384 : 65536;
  const u16* Bp = B + (long)bz*bstr;
  const int m0 = blockIdx.x*64, n0 = blockIdx.y*64;
  float bscale = (MODE==PM_W0) ? *sptr : 1.f;

  f32x4 acc[4];
  #pragma unroll
  for (int j=0;j<4;j++){ acc[j][0]=0.f; acc[j][1]=0.f; acc[j][2]=0.f; acc[j][3]=0.f; }

  const int srow = tid>>2, scol = (tid&3)*16;
  for (int k0=0;k0<256;k0+=64){
    *(int4*)&As[srow][scol]   = *(const int4*)(Ap + (long)(m0+srow)*256 + k0 + scol);
    *(int4*)&As[srow][scol+8] = *(const int4*)(Ap + (long)(m0+srow)*256 + k0 + scol + 8);
    if (MODE==PM_W0){
      #pragma unroll
      for (int s=0;s<2;s++){
        int4 raw = *(const int4*)(Bp + (long)(n0+srow)*256 + k0 + scol + s*8);
        u16* pr = (u16*)&raw; u16 o[8];
        #pragma unroll
        for (int j=0;j<8;j++) o[j] = f2bf(bscale*bf2f(pr[j]));
        *(int4*)&Bs[srow][scol + s*8] = *(int4*)o;
      }
    } else {
      *(int4*)&Bs[srow][scol]   = *(const int4*)(Bp + (long)(n0+srow)*256 + k0 + scol);
      *(int4*)&Bs[srow][scol+8] = *(const int4*)(Bp + (long)(n0+srow)*256 + k0 + scol + 8);
    }
    __syncthreads();
    #pragma unroll
    for (int kb=0;kb<2;kb++){
      s16x8 af = *(const s16x8*)&As[w*16 + ln][kb*32 + q*8];
      #pragma unroll
      for (int nt=0;nt<4;nt++){
        s16x8 bfr = *(const s16x8*)&Bs[nt*16 + ln][kb*32 + q*8];
        acc[nt] = MFMA16(af, bfr, acc[nt]);
      }
    }
    __syncthreads();
  }

  #pragma unroll
  for (int nt=0;nt<4;nt++)
  #pragma unroll
  for (int r=0;r<4;r++){
    int mrow = m0 + w*16 + q*4 + r;
    int ncol = n0 + nt*16 + ln;
    float v = acc[nt][r];
    long idx  = (long)bz*65536 + (long)mrow*256 + ncol;
    long idxt = (long)bz*16384 + (long)ncol*256 + mrow;
    if (MODE==PM_M){
      float wv = bf2f(Wp[idx]), sv = bf2f(Sp[idx]);
      float m = 0.25f*(((mrow==ncol)?13.f:0.f) - 15.f*wv + 7.f*sv - v);
      out[idx] = f2bf(m);
    } else if (MODE==PM_PAIR){
      (half ? out2 : out)[idx] = f2bf(v);
    } else if (MODE==PM_TH){
      out[idxt] = f2bf(v);
    } else if (MODE==PM_THG){
      float g = 0.25f*(13.f*bf2f(Wp[idxt]) - 15.f*bf2f(Sp[idxt]) + 7.f*bf2f(Tp[idxt]) - v);
      out[idxt] = f2bf(g);
    } else if (MODE==PM_THINU){
      if (ncol < 32) out[(long)bz*8192 + (long)ncol*256 + mrow] = f2bf(v*(*sptr));
    } else { // W0, S
      out[idx] = f2bf(v);
    }
  }
}

// ---------------------------------------------------------------------------
// LayerNorm: one wave per row (256 cols), write bf16
// ---------------------------------------------------------------------------
__global__ __launch_bounds__(256)
void kln(const float* __restrict__ y, const float* __restrict__ g, const float* __restrict__ b,
         u16* __restrict__ out)
{
  int w = threadIdx.x>>6, l = threadIdx.x&63;
  long row = (long)blockIdx.x*4 + w;
  float4 v = ((const float4*)(y + row*256))[l];
  float s = v.x+v.y+v.z+v.w;
  #pragma unroll
  for (int m=1;m<64;m<<=1) s += __shfl_xor(s, m);
  float mu = s*(1.0f/256.0f);
  float dx=v.x-mu, dy=v.y-mu, dz=v.z-mu, dw=v.w-mu;
  float s2 = dx*dx+dy*dy+dz*dz+dw*dw;
  #pragma unroll
  for (int m=1;m<64;m<<=1) s2 += __shfl_xor(s2, m);
  float rs = rsqrtf(s2*(1.0f/256.0f) + 1e-5f);
  float4 gg = ((const float4*)g)[l];
  float4 bb = ((const float4*)b)[l];
  ushort4 o;
  o.x = f2bf(dx*rs*gg.x + bb.x);
  o.y = f2bf(dy*rs*gg.y + bb.y);
  o.z = f2bf(dz*rs*gg.z + bb.z);
  o.w = f2bf(dw*rs*gg.w + bb.w);
  *(ushort4*)(out + row*256 + l*4) = o;
}

// ---------------------------------------------------------------------------
// Merged attn2 + attn3v (independent; grid (16,32): x<8 attn2, x>=8 attn3v)
// ---------------------------------------------------------------------------
__global__ __launch_bounds__(256)
void kattn23(const u16* __restrict__ ql, const u16* __restrict__ kl,
             u16* __restrict__ X, u16* __restrict__ XT, float* __restrict__ cs_p,
             const u16* __restrict__ kk, const u16* __restrict__ vv,
             float* __restrict__ num_p, float* __restrict__ den_p)
{
  __shared__ __align__(16) u16 Pbuf[4][64][40];
  __shared__ __align__(16) u16 vT[32][40];
  __shared__ float qrow[32][33];
  __shared__ float psum[32][4];
  __shared__ float rsum[32];
  int bh = blockIdx.y;
  int tid = threadIdx.x, w = tid>>6, l = tid&63, q = l>>4, ln = l&15;

  if (blockIdx.x < 8){
    int r0 = blockIdx.x*32;
    int c = tid;
    #pragma unroll
    for (int i=0;i<4;i++){
      int e = c*4+i; int rr = e>>5, dd = e&31;
      qrow[rr][dd] = bf2f(ql[((long)bh*256 + r0+rr)*32 + dd]);
    }
    float kc[32];
    {
      const u16* kp = kl + ((long)bh*256 + c)*32;
      #pragma unroll
      for (int d=0;d<32;d++) kc[d] = bf2f(kp[d]);
    }
    __syncthreads();
    float er[32]; float colacc = 0.f;
    for (int r=0;r<32;r++){
      float s = 0.f;
      #pragma unroll
      for (int d=0;d<32;d++) s += qrow[r][d]*kc[d];
      float e = __expf(s);
      er[r] = e;
      float wsum = e;
      #pragma unroll
      for (int m=1;m<64;m<<=1) wsum += __shfl_xor(wsum, m);
      if (l==0) psum[r][w] = wsum;
    }
    __syncthreads();
    if (c<32) rsum[c] = psum[c][0]+psum[c][1]+psum[c][2]+psum[c][3];
    __syncthreads();
    for (int r=0;r<32;r++){
      float x = er[r]/rsum[r];
      u16 xb = f2bf(x);
      X [((long)bh*256 + r0+r)*256 + c] = xb;
      XT[((long)bh*256 + c)*256 + r0+r] = xb;
      colacc += x;
    }
    cs_p[(long)blockIdx.x*8192 + bh*256 + c] = colacc;
    return;
  }

  int chunk = blockIdx.x - 8;
  f32x4 z4; z4[0]=0.f; z4[1]=0.f; z4[2]=0.f; z4[3]=0.f;
  f32x4 acc[4][2]; f32x4 dacc[4];
  #pragma unroll
  for (int mt=0;mt<4;mt++){ dacc[mt]=z4; acc[mt][0]=z4; acc[mt][1]=z4; }
  const u16* qlb = ql + (long)bh*8192;
  const u16* kb  = kk + (long)bh*131072;
  const u16* vb  = vv + (long)bh*131072;
  int vn = tid>>3, vd = (tid&7)*4;
  for (int s=0;s<16;s++){
    int n0 = chunk*512 + s*32;
    ushort4 vx = *(const ushort4*)(vb + (long)(n0+vn)*32 + vd);
    vT[vd+0][vn]=vx.x; vT[vd+1][vn]=vx.y; vT[vd+2][vn]=vx.z; vT[vd+3][vn]=vx.w;
    __syncthreads();
    s16x8 bk[2];
    #pragma unroll
    for (int nt=0;nt<2;nt++) bk[nt] = *(const s16x8*)(kb + (long)(n0 + nt*16 + ln)*32 + q*8);
    #pragma unroll
    for (int mt=0;mt<4;mt++){
      s16x8 aq = *(const s16x8*)(qlb + (long)(w*64 + mt*16 + ln)*32 + q*8);
      #pragma unroll
      for (int nt=0;nt<2;nt++){
        f32x4 sf = MFMA16(aq, bk[nt], z4);
        f32x4 ef;
        #pragma unroll
        for (int r=0;r<4;r++) ef[r] = __expf(sf[r]);
        dacc[mt] += ef;
        #pragma unroll
        for (int r=0;r<4;r++) Pbuf[w][mt*16 + q*4 + r][nt*16 + ln] = f2bf(ef[r]);
      }
    }
    #pragma unroll
    for (int mt=0;mt<4;mt++){
      s16x8 ap = *(const s16x8*)&Pbuf[w][mt*16 + ln][q*8];
      #pragma unroll
      for (int nt=0;nt<2;nt++){
        s16x8 bv = *(const s16x8*)&vT[nt*16 + ln][q*8];
        acc[mt][nt] = MFMA16(ap, bv, acc[mt][nt]);
      }
    }
    __syncthreads();
  }
  #pragma unroll
  for (int mt=0;mt<4;mt++)
    #pragma unroll
    for (int r=0;r<4;r++){
      float x = dacc[mt][r];
      x += __shfl_xor(x,1); x += __shfl_xor(x,2); x += __shfl_xor(x,4); x += __shfl_xor(x,8);
      dacc[mt][r] = x;
    }
  long pbase = (long)(chunk*32 + bh);
  #pragma unroll
  for (int mt=0;mt<4;mt++)
    #pragma unroll
    for (int nt=0;nt<2;nt++)
      #pragma unroll
      for (int r=0;r<4;r++){
        int mg = w*64 + mt*16 + q*4 + r;
        num_p[pbase*8192 + (long)mg*32 + nt*16 + ln] = acc[mt][nt][r];
      }
  if (ln==0){
    #pragma unroll
    for (int mt=0;mt<4;mt++)
      #pragma unroll
      for (int r=0;r<4;r++)
        den_p[pbase*256 + w*64 + mt*16 + q*4 + r] = dacc[mt][r];
  }
}

// ---------------------------------------------------------------------------
// ks0w3: WG0 = 1/max colsum; WG 1+bh = w3T prep (coalesced + LDS transpose)
// ---------------------------------------------------------------------------
__global__ __launch_bounds__(256)
void ks0w3(const float* __restrict__ cs_p, float* __restrict__ scal,
           const float* __restrict__ num_p, const float* __restrict__ den_p,
           u16* __restrict__ w3T)
{
  int t = threadIdx.x;
  if (blockIdx.x == 0){
    __shared__ float red[256];
    float m = 0.f;
    for (int i=t;i<8192;i+=256){
      float s = 0.f;
      #pragma unroll
      for (int c=0;c<8;c++) s += cs_p[(long)c*8192 + i];
      m = fmaxf(m, s);
    }
    red[t] = m; __syncthreads();
    for (int s=128;s>0;s>>=1){ if (t<s) red[t] = fmaxf(red[t], red[t+s]); __syncthreads(); }
    if (t==0) scal[0] = 1.0f/red[0];
    return;
  }
  int bh = blockIdx.x - 1;
  __shared__ float lt[32][257];
  for (int i=t;i<8192;i+=256){
    int m = i>>5, d = i&31;
    float sn = 0.f, sd = 0.f;
    #pragma unroll
    for (int c=0;c<8;c++){
      sn += num_p[((long)(c*32+bh))*8192 + i];
      sd += den_p[(c*32+bh)*256 + m];
    }
    lt[d][m] = sn/sd;
  }
  __syncthreads();
  u16* o = w3T + (long)bh*16384;
  for (int j=t;j<16384;j+=256){
    int d = j>>8, m = j&255;
    o[j] = (d<32) ? f2bf(lt[d][m]) : (u16)0;
  }
}

// ---------------------------------------------------------------------------
// attn1 fused + depthwise residual conv:
// aoutb = softmax(q @ k_l^T) @ u + conv33(v)
// ---------------------------------------------------------------------------
__global__ __launch_bounds__(256)
void kattn1u(const u16* __restrict__ qq, const u16* __restrict__ kl, const u16* __restrict__ uT,
             const u16* __restrict__ vv, const float* __restrict__ rw,
             u16* __restrict__ aoutb)
{
  int nch = blockIdx.x, bh = blockIdx.y;
  int b = bh>>3, h = bh&7;
  int tid = threadIdx.x, w = tid>>6, l = tid&63, q = l>>4, ln = l&15;
  __shared__ __align__(16) u16 Pbuf[4][32][40];
  __shared__ __align__(16) u16 vtile[160][36];
  int r0g = nch*128;
  const u16* vb = vv + (long)bh*131072;
  #pragma unroll
  for (int it=0; it<5; it++){
    int slot = tid + it*256;
    int rr = slot>>3, c = (slot&7)*4;
    int s = r0g - 16 + rr;
    ushort4 val; val.x=0; val.y=0; val.z=0; val.w=0;
    if (s>=0 && s<4096) val = *(const ushort4*)(vb + (long)s*32 + c);
    *(ushort4*)&vtile[rr][c] = val;
  }
  __syncthreads();

  f32x4 z4; z4[0]=0.f; z4[1]=0.f; z4[2]=0.f; z4[3]=0.f;
  f32x4 acc[2][2]; f32x4 dacc[2];
  #pragma unroll
  for (int mt=0;mt<2;mt++){ dacc[mt]=z4; acc[mt][0]=z4; acc[mt][1]=z4; }
  const u16* qb  = qq + (long)bh*131072;
  const u16* klb = kl + (long)bh*8192;
  const u16* ub  = uT + (long)bh*8192;
  int r0 = r0g + w*32;
  for (int s=0;s<8;s++){
    s16x8 bk[2];
    #pragma unroll
    for (int nt=0;nt<2;nt++) bk[nt] = *(const s16x8*)(klb + (long)(s*32 + nt*16 + ln)*32 + q*8);
    #pragma unroll
    for (int mt=0;mt<2;mt++){
      s16x8 aq = *(const s16x8*)(qb + (long)(r0 + mt*16 + ln)*32 + q*8);
      #pragma unroll
      for (int nt=0;nt<2;nt++){
        f32x4 sf = MFMA16(aq, bk[nt], z4);
        f32x4 ef;
        #pragma unroll
        for (int r=0;r<4;r++) ef[r] = __expf(sf[r]);
        dacc[mt] += ef;
        #pragma unroll
        for (int r=0;r<4;r++) Pbuf[w][mt*16 + q*4 + r][nt*16 + ln] = f2bf(ef[r]);
      }
    }
    #pragma unroll
    for (int mt=0;mt<2;mt++){
      s16x8 ap = *(const s16x8*)&Pbuf[w][mt*16 + ln][q*8];
      #pragma unroll
      for (int nt=0;nt<2;nt++){
        s16x8 bu = *(const s16x8*)(ub + (long)(nt*16 + ln)*256 + s*32 + q*8);
        acc[mt][nt] = MFMA16(ap, bu, acc[mt][nt]);
      }
    }
  }
  #pragma unroll
  for (int mt=0;mt<2;mt++)
    #pragma unroll
    for (int r=0;r<4;r++){
      float x = dacc[mt][r];
      x += __shfl_xor(x,1); x += __shfl_xor(x,2); x += __shfl_xor(x,4); x += __shfl_xor(x,8);
      dacc[mt][r] = x;
    }

  const float* wp = rw + h*33;
  float w_[33];
  #pragma unroll
  for (int j=0;j<33;j++) w_[j] = wp[j];

  #pragma unroll
  for (int mt=0;mt<2;mt++){
    int nl = w*32 + mt*16 + q*4;
    #pragma unroll
    for (int nt=0;nt<2;nt++){
      int d = nt*16 + ln;
      float vvv[36];
      #pragma unroll
      for (int j=0;j<36;j++) vvv[j] = bf2f(vtile[nl + j][d]);
      #pragma unroll
      for (int r=0;r<4;r++){
        float cv = 0.f;
        #pragma unroll
        for (int j=0;j<33;j++) cv += w_[j]*vvv[r+j];
        int n = r0 + mt*16 + q*4 + r;
        long oidx = ((long)b*4096 + n)*256 + h*32 + d;
        aoutb[oidx] = f2bf(acc[mt][nt][r]/dacc[mt][r] + cv);
      }
    }
  }
}

// ---------------------------------------------------------------------------
// Merged weight transpose+cast: all 4 weights in one launch (grid 1024).
// ---------------------------------------------------------------------------
__global__ __launch_bounds__(256)
void kcvtall(const float* __restrict__ wqkv, const float* __restrict__ wout,
             const float* __restrict__ w1, const float* __restrict__ w2,
             u16* __restrict__ wqkvT, u16* __restrict__ woutT,
             u16* __restrict__ w1T, u16* __restrict__ w2T)
{
  __shared__ float t[32][33];
  int z = blockIdx.x;
  const float* src; u16* dst; int K, Nn, bx, by;
  if (z < 384){      int i=z/192, r=z%192; src=wqkv+(long)i*196608; dst=wqkvT+(long)i*196608; K=256; Nn=768; bx=r%24; by=r/24; }
  else if (z < 512){ int zz=z-384; int i=zz/64, r=zz%64; src=wout+(long)i*65536; dst=woutT+(long)i*65536; K=256; Nn=256; bx=r%8; by=r/8; }
  else if (z < 768){ int zz=z-512; int i=zz/128, r=zz%128; src=w1+(long)i*131072; dst=w1T+(long)i*131072; K=256; Nn=512; bx=r%16; by=r/16; }
  else {             int zz=z-768; int i=zz/128, r=zz%128; src=w2+(long)i*131072; dst=w2T+(long)i*131072; K=512; Nn=256; bx=r%8; by=r/8; }
  int n0 = bx*32, k0 = by*32;
  int tx = threadIdx.x&31, ty = threadIdx.x>>5;
  #pragma unroll
  for (int i=0;i<4;i++) t[ty+i*8][tx] = src[(long)(k0+ty+i*8)*Nn + n0+tx];
  __syncthreads();
  #pragma unroll
  for (int i=0;i<4;i++) dst[(long)(n0+ty+i*8)*K + k0+tx] = f2bf(t[tx][ty+i*8]);
}

// ---------------------------------------------------------------------------
extern "C" void kernel_launch(void* const* d_in, const int* in_sizes, int n_in,
                              void* d_out, int out_size, void* d_ws, size_t ws_size,
                              hipStream_t stream)
{
  const float* x    = (const float*)d_in[0];
  const float* ln1g = (const float*)d_in[1];
  const float* ln1b = (const float*)d_in[2];
  const float* wqkv = (const float*)d_in[3];
  const float* wout = (const float*)d_in[4];
  const float* bout = (const float*)d_in[5];
  const float* resw = (const float*)d_in[6];
  const float* ln2g = (const float*)d_in[7];
  const float* ln2b = (const float*)d_in[8];
  const float* w1   = (const float*)d_in[9];
  const float* b1   = (const float*)d_in[10];
  const float* w2   = (const float*)d_in[11];
  const float* b2   = (const float*)d_in[12];
  float* y = (float*)d_out;
  char* ws = (char*)d_ws;

  u16* xn    = (u16*)(ws + 0);
  u16* qb    = (u16*)(ws + 8388608);
  u16* kb    = (u16*)(ws + 16777216);
  u16* vb    = (u16*)(ws + 25165824);
  u16* ql    = (u16*)(ws + 33554432);
  u16* kl    = (u16*)(ws + 34078720);
  u16* X     = (u16*)(ws + 34603008);
  u16* XT    = (u16*)(ws + 38797312);     // doubles as z~0
  u16* w3T   = (u16*)(ws + 42991616);     // [32][64][256] bf16 (rows>=32 zero)
  u16* g1T   = (u16*)(ws + 44040192);     // [32][64][256]
  u16* aT    = (u16*)(ws + 45088768);     // [32][64][256]
  u16* bT    = (u16*)(ws + 46137344);     // [32][64][256]
  // pinv work region: 6 x 4 MB
  u16* WA    = (u16*)(ws + 51380224);
  u16* WB    = (u16*)(ws + 55574528);
  u16* Sb    = (u16*)(ws + 59768832);
  u16* Mb    = (u16*)(ws + 63963136);
  u16* zA    = (u16*)(ws + 68157440);
  u16* zB    = (u16*)(ws + 72351744);
  float* num_p = (float*)(ws + 76546048);  // 8 MB
  float* den_p = (float*)(ws + 84934656);
  float* cs_p  = (float*)(ws + 85196800);
  float* scal  = (float*)(ws + 85458944);
  u16* uT    = (u16*)(ws + 85459200);
  u16* aoutb = (u16*)(ws + 85983488);
  u16* wqkvT = (u16*)(ws + 94372096);
  u16* woutT = (u16*)(ws + 95158528);
  u16* w1T   = (u16*)(ws + 95420672);
  u16* w2T   = (u16*)(ws + 95944960);
  u16* hdn   = (u16*)(ws + 51380224);      // overlays pinv region (dead by FFN)

  (void)in_sizes; (void)n_in; (void)out_size; (void)ws_size;

  kcvtall<<<1024,256,0,stream>>>(wqkv, wout, w1, w2, wqkvT, woutT, w1T, w2T);

  for (int i=0;i<2;i++){
    kln<<<4096,256,0,stream>>>(i==0 ? x : y, ln1g + i*256, ln1b + i*256, xn);
    kgemm2<EPI_QKV><<<dim3(128,6),256,0,stream>>>(xn, wqkvT + (long)i*196608, 256, 256, 256,
        nullptr, nullptr, 0, qb,kb,vb, ql,kl);
    kattn23<<<dim3(16,32),256,0,stream>>>(ql, kl, X, XT, cs_p, kb, vb, num_p, den_p);
    ks0w3<<<33,256,0,stream>>>(cs_p, scal, num_p, den_p, w3T);

    // ---- pinv: W' = W@M, z~' = z~@M with M = 0.25(13I - 15W + 7S - S@W) ----
    kpinv<PM_W0><<<dim3(4,4,32),256,0,stream>>>(X, X, nullptr, WA, nullptr,
        nullptr, nullptr, nullptr, scal);
    u16 *Wi = WA, *Wo = WB, *zi = XT, *zo = zA;
    for (int it=0; it<5; it++){
      kpinv<PM_S><<<dim3(4,4,32),256,0,stream>>>(Wi, Wi, nullptr, Sb, nullptr,
          nullptr, nullptr, nullptr, nullptr);
      kpinv<PM_M><<<dim3(4,4,32),256,0,stream>>>(Sb, Wi, nullptr, Mb, nullptr,
          Wi, Sb, nullptr, nullptr);
      kpinv<PM_PAIR><<<dim3(4,4,64),256,0,stream>>>(Wi, Mb, zi, Wo, zo,
          nullptr, nullptr, nullptr, nullptr);
      u16* t = Wi; Wi = Wo; Wo = t;
      zi = zo; zo = (zo == zA) ? zB : zA;
    }
    // thin tail: a=W5@w3, b=W5@a, c=W5@b (g1 = .25(13w3-15a+7b-c)); u=z5@g1*s0
    kpinv<PM_TH><<<dim3(4,1,32),256,0,stream>>>(Wi, w3T, nullptr, aT, nullptr,
        nullptr, nullptr, nullptr, nullptr);
    kpinv<PM_TH><<<dim3(4,1,32),256,0,stream>>>(Wi, aT, nullptr, bT, nullptr,
        nullptr, nullptr, nullptr, nullptr);
    kpinv<PM_THG><<<dim3(4,1,32),256,0,stream>>>(Wi, bT, nullptr, g1T, nullptr,
        w3T, aT, bT, nullptr);
    kpinv<PM_THINU><<<dim3(4,1,32),256,0,stream>>>(zi, g1T, nullptr, uT, nullptr,
        nullptr, nullptr, nullptr, scal);

    kattn1u<<<dim3(32,32),256,0,stream>>>(qb, kl, uT, vb, resw + i*264, aoutb);
    kgemm<EPI_BIAS_RES><<<dim3(128,4),256,0,stream>>>(aoutb, woutT + (long)i*65536, 256,256,256,
        bout + i*256, i==0 ? x : y, y, nullptr, 256);
    kln<<<4096,256,0,stream>>>(y, ln2g + i*256, ln2b + i*256, xn);
    kgemm2<EPI_BIAS_GELU><<<dim3(128,4),256,0,stream>>>(xn, w1T + (long)i*131072, 256, 256, 256,
        b1 + i*512, hdn, 512, nullptr,nullptr,nullptr, nullptr,nullptr);
    kgemm<EPI_BIAS_RES><<<dim3(128,4),256,0,stream>>>(hdn, w2T + (long)i*131072, 512,512,512,
        b2 + i*256, y, y, nullptr, 256);
  }
}

// Round 17
// 640.153 us; speedup vs baseline: 1.1849x; 1.1060x over previous
//
#include <hip/hip_runtime.h>
#include <math.h>

typedef float f32x4 __attribute__((ext_vector_type(4)));
typedef short s16x8 __attribute__((ext_vector_type(8)));
typedef unsigned short u16;
typedef unsigned int u32;

#define MFMA16(a,b,c) __builtin_amdgcn_mfma_f32_16x16x32_bf16((a),(b),(c),0,0,0)
#define AS1 __attribute__((address_space(1)))
#define AS3 __attribute__((address_space(3)))

__device__ __forceinline__ void dma16(const u16* g, u16* l){
  __builtin_amdgcn_global_load_lds((const AS1 u32*)g, (AS3 u32*)l, 16, 0, 0);
}

__device__ __forceinline__ float bf2f(u16 u){
  union { unsigned int i; float f; } v; v.i = ((unsigned int)u)<<16; return v.f;
}
__device__ __forceinline__ u16 f2bf(float f){
  union { float f; unsigned int i; } v; v.f = f;
  unsigned int x = v.i;
  return (u16)((x + 0x7fffu + ((x>>16)&1u))>>16);
}

enum { EPI_QKV=0, EPI_PINV=1, EPI_BIAS_RES=2, EPI_BIAS_GELU=3 };

// ---------------------------------------------------------------------------
// kgemm: BM=128, BN=64, BK=32 (N=256 outputs: RES / RES2).
// DMA staging, unpadded LDS + chunk-XOR swizzle.
// ---------------------------------------------------------------------------
template<int EPI>
__global__ __launch_bounds__(256)
void kgemm(const u16* __restrict__ A, const u16* __restrict__ BT, int K, int lda, int ldb,
           const float* __restrict__ bias, const float* __restrict__ base,
           float* __restrict__ resout,
           u16* __restrict__ outb, int ldc)
{
  __shared__ __align__(16) u16 As[128*32];
  __shared__ __align__(16) u16 Bs[64*32];
  const int tid = threadIdx.x;
  const int w = tid>>6, l = tid&63, q = l>>4, ln = l&15;
  const int m0 = blockIdx.x*128, n0 = blockIdx.y*64;
  const int lrow = l>>2, lch = l&3;

  f32x4 acc[2][4];
  #pragma unroll
  for (int i=0;i<2;i++)
    #pragma unroll
    for (int j=0;j<4;j++){ acc[i][j][0]=0.f; acc[i][j][1]=0.f; acc[i][j][2]=0.f; acc[i][j][3]=0.f; }

  for (int k0=0; k0<K; k0+=32){
    #pragma unroll
    for (int c=0;c<2;c++){
      int row = 32*w + 16*c + lrow;
      int gch = lch ^ ((row>>1)&3);
      dma16(A + (long)(m0+row)*lda + k0 + gch*8, &As[(32*w+16*c)*32]);
    }
    {
      int row = 16*w + lrow;
      int gch = lch ^ ((row>>1)&3);
      dma16(BT + (long)(n0+row)*ldb + k0 + gch*8, &Bs[(16*w)*32]);
    }
    __syncthreads();
    s16x8 af[2], bfr[4];
    #pragma unroll
    for (int mt=0;mt<2;mt++){
      int row = w*32 + mt*16 + ln;
      af[mt] = *(const s16x8*)&As[row*32 + ((q ^ ((row>>1)&3))<<3)];
    }
    #pragma unroll
    for (int nt=0;nt<4;nt++){
      int row = nt*16 + ln;
      bfr[nt] = *(const s16x8*)&Bs[row*32 + ((q ^ ((row>>1)&3))<<3)];
    }
    #pragma unroll
    for (int mt=0;mt<2;mt++)
      #pragma unroll
      for (int nt=0;nt<4;nt++)
        acc[mt][nt] = MFMA16(af[mt], bfr[nt], acc[mt][nt]);
    __syncthreads();
  }

  #pragma unroll
  for (int mt=0;mt<2;mt++)
  #pragma unroll
  for (int nt=0;nt<4;nt++)
  #pragma unroll
  for (int r=0;r<4;r++){
    int mrow = m0 + w*32 + mt*16 + q*4 + r;
    int ncol = n0 + nt*16 + ln;
    float v = acc[mt][nt][r];
    if (EPI==EPI_BIAS_RES){
      long idx = (long)mrow*ldc + ncol;
      resout[idx] = base[idx] + v + bias[ncol];
    } else {
      outb[(long)mrow*ldc + ncol] = f2bf(v);
    }
  }
}

// ---------------------------------------------------------------------------
// kgemm2: BM=128, BN=128, BK=32, 4x4 frags/wave; DMA staging + swizzle.
// Wide GEMMs: QKV (N=768, emits landmark means) and FFN1+GELU (N=512).
// ---------------------------------------------------------------------------
template<int EPI>
__global__ __launch_bounds__(256)
void kgemm2(const u16* __restrict__ A, const u16* __restrict__ BT, int K, int lda, int ldb,
            const float* __restrict__ bias, u16* __restrict__ outb, int ldc,
            u16* __restrict__ qo, u16* __restrict__ ko, u16* __restrict__ vo,
            u16* __restrict__ qlm, u16* __restrict__ klm)
{
  __shared__ __align__(16) u16 As[128*32];
  __shared__ __align__(16) u16 Bs[128*32];
  const int tid = threadIdx.x;
  const int w = tid>>6, wy = w>>1, wx = w&1, l = tid&63, q = l>>4, ln = l&15;
  const int m0 = blockIdx.x*128, n0 = blockIdx.y*128;
  const int lrow = l>>2, lch = l&3;

  f32x4 acc[4][4];
  #pragma unroll
  for (int i=0;i<4;i++)
    #pragma unroll
    for (int j=0;j<4;j++){ acc[i][j][0]=0.f; acc[i][j][1]=0.f; acc[i][j][2]=0.f; acc[i][j][3]=0.f; }

  for (int k0=0; k0<K; k0+=32){
    #pragma unroll
    for (int c=0;c<2;c++){
      int row = 32*w + 16*c + lrow;
      int gch = lch ^ ((row>>1)&3);
      dma16(A + (long)(m0+row)*lda + k0 + gch*8, &As[(32*w+16*c)*32]);
      dma16(BT + (long)(n0+row)*ldb + k0 + gch*8, &Bs[(32*w+16*c)*32]);
    }
    __syncthreads();
    s16x8 af[4], bfr[4];
    #pragma unroll
    for (int mt=0;mt<4;mt++){
      int row = wy*64 + mt*16 + ln;
      af[mt] = *(const s16x8*)&As[row*32 + ((q ^ ((row>>1)&3))<<3)];
    }
    #pragma unroll
    for (int nt=0;nt<4;nt++){
      int row = wx*64 + nt*16 + ln;
      bfr[nt] = *(const s16x8*)&Bs[row*32 + ((q ^ ((row>>1)&3))<<3)];
    }
    #pragma unroll
    for (int mt=0;mt<4;mt++)
      #pragma unroll
      for (int nt=0;nt<4;nt++)
        acc[mt][nt] = MFMA16(af[mt], bfr[nt], acc[mt][nt]);
    __syncthreads();
  }

  #pragma unroll
  for (int mt=0;mt<4;mt++)
  #pragma unroll
  for (int nt=0;nt<4;nt++){
    int ncol = n0 + wx*64 + nt*16 + ln;
    if (EPI==EPI_QKV){
      int sel = ncol>>8, hd = ncol&255, h = hd>>5, d = hd&31;
      u16* dst = sel==0 ? qo : (sel==1 ? ko : vo);
      float sc2 = (sel==0) ? 0.17677669529663689f : 1.f;   // dh^-0.5 on q
      float s = 0.f;
      #pragma unroll
      for (int r=0;r<4;r++){
        int mrow = m0 + wy*64 + mt*16 + q*4 + r;
        int b = mrow>>12, n = mrow&4095;
        float v = acc[mt][nt][r]*sc2;
        dst[(((long)(b*8+h)*4096 + n)<<5) + d] = f2bf(v);
        s += v;
      }
      if (sel < 2){
        s += __shfl_xor(s, 16);
        s += __shfl_xor(s, 32);
        if (q == 0){
          int mrow0 = m0 + wy*64 + mt*16;
          int b = mrow0>>12, grp = (mrow0&4095)>>4;
          u16* ldst = (sel==0) ? qlm : klm;
          ldst[(((long)(b*8+h)*256 + grp)<<5) + d] = f2bf(s*(1.0f/16.0f));
        }
      }
    } else { // EPI_BIAS_GELU
      #pragma unroll
      for (int r=0;r<4;r++){
        int mrow = m0 + wy*64 + mt*16 + q*4 + r;
        float x = acc[mt][nt][r] + bias[ncol];
        float g = 0.5f*x*(1.0f + erff(x*0.70710678118654752f));
        outb[(long)mrow*ldc + ncol] = f2bf(g);
      }
    }
  }
}

// ---------------------------------------------------------------------------
// Batched pinv GEMM, 256-K per batch, 64x64 tiles, BK=64.
// DMA staging into unpadded [64][64] slabs, 8-chunk XOR swizzle:
// slot (row,s) holds global chunk s^((row>>1)&7); fragment reads 2-way-free.
// W0 mode keeps manual scaled-B staging (same swizzled layout).
// ---------------------------------------------------------------------------
enum { PM_W0=0, PM_S=1, PM_M=2, PM_PAIR=3, PM_TH=4, PM_THG=5, PM_THINU=6 };

template<int MODE>
__global__ __launch_bounds__(256)
void kpinv(const u16* __restrict__ A, const u16* __restrict__ B,
           const u16* __restrict__ A2,
           u16* __restrict__ out, u16* __restrict__ out2,
           const u16* __restrict__ Wp, const u16* __restrict__ Sp,
           const u16* __restrict__ Tp,
           const float* __restrict__ sptr)
{
  __shared__ __align__(16) u16 As[64*64];
  __shared__ __align__(16) u16 Bs[64*64];
  const int tid=threadIdx.x, w=tid>>6, l=tid&63, q=l>>4, ln=l&15;
  int bz = blockIdx.z, half = 0;
  if (MODE==PM_PAIR){ half = bz>>5; bz &= 31; }
  const u16* Ap = ((MODE==PM_PAIR && half) ? A2 : A) + (long)bz*65536;
  const long bstr = (MODE>=PM_TH) ? 16384 : 65536;
  const u16* Bp = B + (long)bz*bstr;
  const int m0 = blockIdx.x*64, n0 = blockIdx.y*64;
  float bscale = (MODE==PM_W0) ? *sptr : 1.f;

  f32x4 acc[4];
  #pragma unroll
  for (int j=0;j<4;j++){ acc[j][0]=0.f; acc[j][1]=0.f; acc[j][2]=0.f; acc[j][3]=0.f; }

  const int drow = l>>3, dch = l&7;
  for (int k0=0;k0<256;k0+=64){
    #pragma unroll
    for (int c=0;c<2;c++){
      int rbase = w*16 + c*8;
      int row = rbase + drow;
      int gch = dch ^ ((row>>1)&7);
      dma16(Ap + (long)(m0+row)*256 + k0 + gch*8, &As[rbase*64]);
    }
    if (MODE==PM_W0){
      int row = tid>>2;
      #pragma unroll
      for (int s=0;s<2;s++){
        int sch = (tid&3)*2 + s;
        int gch = sch ^ ((row>>1)&7);
        int4 raw = *(const int4*)(Bp + (long)(n0+row)*256 + k0 + gch*8);
        u16* pr = (u16*)&raw; u16 o[8];
        #pragma unroll
        for (int j=0;j<8;j++) o[j] = f2bf(bscale*bf2f(pr[j]));
        *(int4*)&Bs[row*64 + sch*8] = *(int4*)o;
      }
    } else {
      #pragma unroll
      for (int c=0;c<2;c++){
        int rbase = w*16 + c*8;
        int row = rbase + drow;
        int gch = dch ^ ((row>>1)&7);
        dma16(Bp + (long)(n0+row)*256 + k0 + gch*8, &Bs[rbase*64]);
      }
    }
    __syncthreads();
    #pragma unroll
    for (int kb=0;kb<2;kb++){
      int arow = w*16 + ln;
      s16x8 af = *(const s16x8*)&As[arow*64 + (((kb*4+q) ^ ((arow>>1)&7))<<3)];
      #pragma unroll
      for (int nt=0;nt<4;nt++){
        int brow = nt*16 + ln;
        s16x8 bfr = *(const s16x8*)&Bs[brow*64 + (((kb*4+q) ^ ((brow>>1)&7))<<3)];
        acc[nt] = MFMA16(af, bfr, acc[nt]);
      }
    }
    __syncthreads();
  }

  #pragma unroll
  for (int nt=0;nt<4;nt++)
  #pragma unroll
  for (int r=0;r<4;r++){
    int mrow = m0 + w*16 + q*4 + r;
    int ncol = n0 + nt*16 + ln;
    float v = acc[nt][r];
    long idx  = (long)bz*65536 + (long)mrow*256 + ncol;
    long idxt = (long)bz*16384 + (long)ncol*256 + mrow;
    if (MODE==PM_M){
      float wv = bf2f(Wp[idx]), sv = bf2f(Sp[idx]);
      float m = 0.25f*(((mrow==ncol)?13.f:0.f) - 15.f*wv + 7.f*sv - v);
      out[idx] = f2bf(m);
    } else if (MODE==PM_PAIR){
      (half ? out2 : out)[idx] = f2bf(v);
    } else if (MODE==PM_TH){
      out[idxt] = f2bf(v);
    } else if (MODE==PM_THG){
      float g = 0.25f*(13.f*bf2f(Wp[idxt]) - 15.f*bf2f(Sp[idxt]) + 7.f*bf2f(Tp[idxt]) - v);
      out[idxt] = f2bf(g);
    } else if (MODE==PM_THINU){
      if (ncol < 32) out[(long)bz*8192 + (long)ncol*256 + mrow] = f2bf(v*(*sptr));
    } else { // W0, S
      out[idx] = f2bf(v);
    }
  }
}

// ---------------------------------------------------------------------------
// LayerNorm: one wave per row (256 cols), write bf16
// ---------------------------------------------------------------------------
__global__ __launch_bounds__(256)
void kln(const float* __restrict__ y, const float* __restrict__ g, const float* __restrict__ b,
         u16* __restrict__ out)
{
  int w = threadIdx.x>>6, l = threadIdx.x&63;
  long row = (long)blockIdx.x*4 + w;
  float4 v = ((const float4*)(y + row*256))[l];
  float s = v.x+v.y+v.z+v.w;
  #pragma unroll
  for (int m=1;m<64;m<<=1) s += __shfl_xor(s, m);
  float mu = s*(1.0f/256.0f);
  float dx=v.x-mu, dy=v.y-mu, dz=v.z-mu, dw=v.w-mu;
  float s2 = dx*dx+dy*dy+dz*dz+dw*dw;
  #pragma unroll
  for (int m=1;m<64;m<<=1) s2 += __shfl_xor(s2, m);
  float rs = rsqrtf(s2*(1.0f/256.0f) + 1e-5f);
  float4 gg = ((const float4*)g)[l];
  float4 bb = ((const float4*)b)[l];
  ushort4 o;
  o.x = f2bf(dx*rs*gg.x + bb.x);
  o.y = f2bf(dy*rs*gg.y + bb.y);
  o.z = f2bf(dz*rs*gg.z + bb.z);
  o.w = f2bf(dw*rs*gg.w + bb.w);
  *(ushort4*)(out + row*256 + l*4) = o;
}

// ---------------------------------------------------------------------------
// Merged attn2 + attn3v (independent; grid (16,32): x<8 attn2, x>=8 attn3v)
// ---------------------------------------------------------------------------
__global__ __launch_bounds__(256)
void kattn23(const u16* __restrict__ ql, const u16* __restrict__ kl,
             u16* __restrict__ X, u16* __restrict__ XT, float* __restrict__ cs_p,
             const u16* __restrict__ kk, const u16* __restrict__ vv,
             float* __restrict__ num_p, float* __restrict__ den_p)
{
  __shared__ __align__(16) u16 Pbuf[4][64][40];
  __shared__ __align__(16) u16 vT[32][40];
  __shared__ float qrow[32][33];
  __shared__ float psum[32][4];
  __shared__ float rsum[32];
  int bh = blockIdx.y;
  int tid = threadIdx.x, w = tid>>6, l = tid&63, q = l>>4, ln = l&15;

  if (blockIdx.x < 8){
    int r0 = blockIdx.x*32;
    int c = tid;
    #pragma unroll
    for (int i=0;i<4;i++){
      int e = c*4+i; int rr = e>>5, dd = e&31;
      qrow[rr][dd] = bf2f(ql[((long)bh*256 + r0+rr)*32 + dd]);
    }
    float kc[32];
    {
      const u16* kp = kl + ((long)bh*256 + c)*32;
      #pragma unroll
      for (int d=0;d<32;d++) kc[d] = bf2f(kp[d]);
    }
    __syncthreads();
    float er[32]; float colacc = 0.f;
    for (int r=0;r<32;r++){
      float s = 0.f;
      #pragma unroll
      for (int d=0;d<32;d++) s += qrow[r][d]*kc[d];
      float e = __expf(s);
      er[r] = e;
      float wsum = e;
      #pragma unroll
      for (int m=1;m<64;m<<=1) wsum += __shfl_xor(wsum, m);
      if (l==0) psum[r][w] = wsum;
    }
    __syncthreads();
    if (c<32) rsum[c] = psum[c][0]+psum[c][1]+psum[c][2]+psum[c][3];
    __syncthreads();
    for (int r=0;r<32;r++){
      float x = er[r]/rsum[r];
      u16 xb = f2bf(x);
      X [((long)bh*256 + r0+r)*256 + c] = xb;
      XT[((long)bh*256 + c)*256 + r0+r] = xb;
      colacc += x;
    }
    cs_p[(long)blockIdx.x*8192 + bh*256 + c] = colacc;
    return;
  }

  int chunk = blockIdx.x - 8;
  f32x4 z4; z4[0]=0.f; z4[1]=0.f; z4[2]=0.f; z4[3]=0.f;
  f32x4 acc[4][2]; f32x4 dacc[4];
  #pragma unroll
  for (int mt=0;mt<4;mt++){ dacc[mt]=z4; acc[mt][0]=z4; acc[mt][1]=z4; }
  const u16* qlb = ql + (long)bh*8192;
  const u16* kb  = kk + (long)bh*131072;
  const u16* vb  = vv + (long)bh*131072;
  int vn = tid>>3, vd = (tid&7)*4;
  for (int s=0;s<16;s++){
    int n0 = chunk*512 + s*32;
    ushort4 vx = *(const ushort4*)(vb + (long)(n0+vn)*32 + vd);
    vT[vd+0][vn]=vx.x; vT[vd+1][vn]=vx.y; vT[vd+2][vn]=vx.z; vT[vd+3][vn]=vx.w;
    __syncthreads();
    s16x8 bk[2];
    #pragma unroll
    for (int nt=0;nt<2;nt++) bk[nt] = *(const s16x8*)(kb + (long)(n0 + nt*16 + ln)*32 + q*8);
    #pragma unroll
    for (int mt=0;mt<4;mt++){
      s16x8 aq = *(const s16x8*)(qlb + (long)(w*64 + mt*16 + ln)*32 + q*8);
      #pragma unroll
      for (int nt=0;nt<2;nt++){
        f32x4 sf = MFMA16(aq, bk[nt], z4);
        f32x4 ef;
        #pragma unroll
        for (int r=0;r<4;r++) ef[r] = __expf(sf[r]);
        dacc[mt] += ef;
        #pragma unroll
        for (int r=0;r<4;r++) Pbuf[w][mt*16 + q*4 + r][nt*16 + ln] = f2bf(ef[r]);
      }
    }
    #pragma unroll
    for (int mt=0;mt<4;mt++){
      s16x8 ap = *(const s16x8*)&Pbuf[w][mt*16 + ln][q*8];
      #pragma unroll
      for (int nt=0;nt<2;nt++){
        s16x8 bv = *(const s16x8*)&vT[nt*16 + ln][q*8];
        acc[mt][nt] = MFMA16(ap, bv, acc[mt][nt]);
      }
    }
    __syncthreads();
  }
  #pragma unroll
  for (int mt=0;mt<4;mt++)
    #pragma unroll
    for (int r=0;r<4;r++){
      float x = dacc[mt][r];
      x += __shfl_xor(x,1); x += __shfl_xor(x,2); x += __shfl_xor(x,4); x += __shfl_xor(x,8);
      dacc[mt][r] = x;
    }
  long pbase = (long)(chunk*32 + bh);
  #pragma unroll
  for (int mt=0;mt<4;mt++)
    #pragma unroll
    for (int nt=0;nt<2;nt++)
      #pragma unroll
      for (int r=0;r<4;r++){
        int mg = w*64 + mt*16 + q*4 + r;
        num_p[pbase*8192 + (long)mg*32 + nt*16 + ln] = acc[mt][nt][r];
      }
  if (ln==0){
    #pragma unroll
    for (int mt=0;mt<4;mt++)
      #pragma unroll
      for (int r=0;r<4;r++)
        den_p[pbase*256 + w*64 + mt*16 + q*4 + r] = dacc[mt][r];
  }
}

// ---------------------------------------------------------------------------
// ks0w3: WG0 = 1/max colsum; WG 1+bh = w3T prep (coalesced + LDS transpose)
// ---------------------------------------------------------------------------
__global__ __launch_bounds__(256)
void ks0w3(const float* __restrict__ cs_p, float* __restrict__ scal,
           const float* __restrict__ num_p, const float* __restrict__ den_p,
           u16* __restrict__ w3T)
{
  int t = threadIdx.x;
  if (blockIdx.x == 0){
    __shared__ float red[256];
    float m = 0.f;
    for (int i=t;i<8192;i+=256){
      float s = 0.f;
      #pragma unroll
      for (int c=0;c<8;c++) s += cs_p[(long)c*8192 + i];
      m = fmaxf(m, s);
    }
    red[t] = m; __syncthreads();
    for (int s=128;s>0;s>>=1){ if (t<s) red[t] = fmaxf(red[t], red[t+s]); __syncthreads(); }
    if (t==0) scal[0] = 1.0f/red[0];
    return;
  }
  int bh = blockIdx.x - 1;
  __shared__ float lt[32][257];
  for (int i=t;i<8192;i+=256){
    int m = i>>5, d = i&31;
    float sn = 0.f, sd = 0.f;
    #pragma unroll
    for (int c=0;c<8;c++){
      sn += num_p[((long)(c*32+bh))*8192 + i];
      sd += den_p[(c*32+bh)*256 + m];
    }
    lt[d][m] = sn/sd;
  }
  __syncthreads();
  u16* o = w3T + (long)bh*16384;
  for (int j=t;j<16384;j+=256){
    int d = j>>8, m = j&255;
    o[j] = (d<32) ? f2bf(lt[d][m]) : (u16)0;
  }
}

// ---------------------------------------------------------------------------
// attn1 fused + depthwise residual conv:
// aoutb = softmax(q @ k_l^T) @ u + conv33(v)
// ---------------------------------------------------------------------------
__global__ __launch_bounds__(256)
void kattn1u(const u16* __restrict__ qq, const u16* __restrict__ kl, const u16* __restrict__ uT,
             const u16* __restrict__ vv, const float* __restrict__ rw,
             u16* __restrict__ aoutb)
{
  int nch = blockIdx.x, bh = blockIdx.y;
  int b = bh>>3, h = bh&7;
  int tid = threadIdx.x, w = tid>>6, l = tid&63, q = l>>4, ln = l&15;
  __shared__ __align__(16) u16 Pbuf[4][32][40];
  __shared__ __align__(16) u16 vtile[160][36];
  int r0g = nch*128;
  const u16* vb = vv + (long)bh*131072;
  #pragma unroll
  for (int it=0; it<5; it++){
    int slot = tid + it*256;
    int rr = slot>>3, c = (slot&7)*4;
    int s = r0g - 16 + rr;
    ushort4 val; val.x=0; val.y=0; val.z=0; val.w=0;
    if (s>=0 && s<4096) val = *(const ushort4*)(vb + (long)s*32 + c);
    *(ushort4*)&vtile[rr][c] = val;
  }
  __syncthreads();

  f32x4 z4; z4[0]=0.f; z4[1]=0.f; z4[2]=0.f; z4[3]=0.f;
  f32x4 acc[2][2]; f32x4 dacc[2];
  #pragma unroll
  for (int mt=0;mt<2;mt++){ dacc[mt]=z4; acc[mt][0]=z4; acc[mt][1]=z4; }
  const u16* qb  = qq + (long)bh*131072;
  const u16* klb = kl + (long)bh*8192;
  const u16* ub  = uT + (long)bh*8192;
  int r0 = r0g + w*32;
  for (int s=0;s<8;s++){
    s16x8 bk[2];
    #pragma unroll
    for (int nt=0;nt<2;nt++) bk[nt] = *(const s16x8*)(klb + (long)(s*32 + nt*16 + ln)*32 + q*8);
    #pragma unroll
    for (int mt=0;mt<2;mt++){
      s16x8 aq = *(const s16x8*)(qb + (long)(r0 + mt*16 + ln)*32 + q*8);
      #pragma unroll
      for (int nt=0;nt<2;nt++){
        f32x4 sf = MFMA16(aq, bk[nt], z4);
        f32x4 ef;
        #pragma unroll
        for (int r=0;r<4;r++) ef[r] = __expf(sf[r]);
        dacc[mt] += ef;
        #pragma unroll
        for (int r=0;r<4;r++) Pbuf[w][mt*16 + q*4 + r][nt*16 + ln] = f2bf(ef[r]);
      }
    }
    #pragma unroll
    for (int mt=0;mt<2;mt++){
      s16x8 ap = *(const s16x8*)&Pbuf[w][mt*16 + ln][q*8];
      #pragma unroll
      for (int nt=0;nt<2;nt++){
        s16x8 bu = *(const s16x8*)(ub + (long)(nt*16 + ln)*256 + s*32 + q*8);
        acc[mt][nt] = MFMA16(ap, bu, acc[mt][nt]);
      }
    }
  }
  #pragma unroll
  for (int mt=0;mt<2;mt++)
    #pragma unroll
    for (int r=0;r<4;r++){
      float x = dacc[mt][r];
      x += __shfl_xor(x,1); x += __shfl_xor(x,2); x += __shfl_xor(x,4); x += __shfl_xor(x,8);
      dacc[mt][r] = x;
    }

  const float* wp = rw + h*33;
  float w_[33];
  #pragma unroll
  for (int j=0;j<33;j++) w_[j] = wp[j];

  #pragma unroll
  for (int mt=0;mt<2;mt++){
    int nl = w*32 + mt*16 + q*4;
    #pragma unroll
    for (int nt=0;nt<2;nt++){
      int d = nt*16 + ln;
      float vvv[36];
      #pragma unroll
      for (int j=0;j<36;j++) vvv[j] = bf2f(vtile[nl + j][d]);
      #pragma unroll
      for (int r=0;r<4;r++){
        float cv = 0.f;
        #pragma unroll
        for (int j=0;j<33;j++) cv += w_[j]*vvv[r+j];
        int n = r0 + mt*16 + q*4 + r;
        long oidx = ((long)b*4096 + n)*256 + h*32 + d;
        aoutb[oidx] = f2bf(acc[mt][nt][r]/dacc[mt][r] + cv);
      }
    }
  }
}

// ---------------------------------------------------------------------------
// Merged weight transpose+cast: all 4 weights in one launch (grid 1024).
// ---------------------------------------------------------------------------
__global__ __launch_bounds__(256)
void kcvtall(const float* __restrict__ wqkv, const float* __restrict__ wout,
             const float* __restrict__ w1, const float* __restrict__ w2,
             u16* __restrict__ wqkvT, u16* __restrict__ woutT,
             u16* __restrict__ w1T, u16* __restrict__ w2T)
{
  __shared__ float t[32][33];
  int z = blockIdx.x;
  const float* src; u16* dst; int K, Nn, bx, by;
  if (z < 384){      int i=z/192, r=z%192; src=wqkv+(long)i*196608; dst=wqkvT+(long)i*196608; K=256; Nn=768; bx=r%24; by=r/24; }
  else if (z < 512){ int zz=z-384; int i=zz/64, r=zz%64; src=wout+(long)i*65536; dst=woutT+(long)i*65536; K=256; Nn=256; bx=r%8; by=r/8; }
  else if (z < 768){ int zz=z-512; int i=zz/128, r=zz%128; src=w1+(long)i*131072; dst=w1T+(long)i*131072; K=256; Nn=512; bx=r%16; by=r/16; }
  else {             int zz=z-768; int i=zz/128, r=zz%128; src=w2+(long)i*131072; dst=w2T+(long)i*131072; K=512; Nn=256; bx=r%8; by=r/8; }
  int n0 = bx*32, k0 = by*32;
  int tx = threadIdx.x&31, ty = threadIdx.x>>5;
  #pragma unroll
  for (int i=0;i<4;i++) t[ty+i*8][tx] = src[(long)(k0+ty+i*8)*Nn + n0+tx];
  __syncthreads();
  #pragma unroll
  for (int i=0;i<4;i++) dst[(long)(n0+ty+i*8)*K + k0+tx] = f2bf(t[tx][ty+i*8]);
}

// ---------------------------------------------------------------------------
extern "C" void kernel_launch(void* const* d_in, const int* in_sizes, int n_in,
                              void* d_out, int out_size, void* d_ws, size_t ws_size,
                              hipStream_t stream)
{
  const float* x    = (const float*)d_in[0];
  const float* ln1g = (const float*)d_in[1];
  const float* ln1b = (const float*)d_in[2];
  const float* wqkv = (const float*)d_in[3];
  const float* wout = (const float*)d_in[4];
  const float* bout = (const float*)d_in[5];
  const float* resw = (const float*)d_in[6];
  const float* ln2g = (const float*)d_in[7];
  const float* ln2b = (const float*)d_in[8];
  const float* w1   = (const float*)d_in[9];
  const float* b1   = (const float*)d_in[10];
  const float* w2   = (const float*)d_in[11];
  const float* b2   = (const float*)d_in[12];
  float* y = (float*)d_out;
  char* ws = (char*)d_ws;

  u16* xn    = (u16*)(ws + 0);
  u16* qb    = (u16*)(ws + 8388608);
  u16* kb    = (u16*)(ws + 16777216);
  u16* vb    = (u16*)(ws + 25165824);
  u16* ql    = (u16*)(ws + 33554432);
  u16* kl    = (u16*)(ws + 34078720);
  u16* X     = (u16*)(ws + 34603008);
  u16* XT    = (u16*)(ws + 38797312);     // doubles as z~0
  u16* w3T   = (u16*)(ws + 42991616);     // [32][64][256] bf16 (rows>=32 zero)
  u16* g1T   = (u16*)(ws + 44040192);     // [32][64][256]
  u16* aT    = (u16*)(ws + 45088768);     // [32][64][256]
  u16* bT    = (u16*)(ws + 46137344);     // [32][64][256]
  // pinv work region: 6 x 4 MB
  u16* WA    = (u16*)(ws + 51380224);
  u16* WB    = (u16*)(ws + 55574528);
  u16* Sb    = (u16*)(ws + 59768832);
  u16* Mb    = (u16*)(ws + 63963136);
  u16* zA    = (u16*)(ws + 68157440);
  u16* zB    = (u16*)(ws + 72351744);
  float* num_p = (float*)(ws + 76546048);  // 8 MB
  float* den_p = (float*)(ws + 84934656);
  float* cs_p  = (float*)(ws + 85196800);
  float* scal  = (float*)(ws + 85458944);
  u16* uT    = (u16*)(ws + 85459200);
  u16* aoutb = (u16*)(ws + 85983488);
  u16* wqkvT = (u16*)(ws + 94372096);
  u16* woutT = (u16*)(ws + 95158528);
  u16* w1T   = (u16*)(ws + 95420672);
  u16* w2T   = (u16*)(ws + 95944960);
  u16* hdn   = (u16*)(ws + 51380224);      // overlays pinv region (dead by FFN)

  (void)in_sizes; (void)n_in; (void)out_size; (void)ws_size;

  kcvtall<<<1024,256,0,stream>>>(wqkv, wout, w1, w2, wqkvT, woutT, w1T, w2T);

  for (int i=0;i<2;i++){
    kln<<<4096,256,0,stream>>>(i==0 ? x : y, ln1g + i*256, ln1b + i*256, xn);
    kgemm2<EPI_QKV><<<dim3(128,6),256,0,stream>>>(xn, wqkvT + (long)i*196608, 256, 256, 256,
        nullptr, nullptr, 0, qb,kb,vb, ql,kl);
    kattn23<<<dim3(16,32),256,0,stream>>>(ql, kl, X, XT, cs_p, kb, vb, num_p, den_p);
    ks0w3<<<33,256,0,stream>>>(cs_p, scal, num_p, den_p, w3T);

    // ---- pinv: W' = W@M, z~' = z~@M with M = 0.25(13I - 15W + 7S - S@W) ----
    kpinv<PM_W0><<<dim3(4,4,32),256,0,stream>>>(X, X, nullptr, WA, nullptr,
        nullptr, nullptr, nullptr, scal);
    u16 *Wi = WA, *Wo = WB, *zi = XT, *zo = zA;
    for (int it=0; it<5; it++){
      kpinv<PM_S><<<dim3(4,4,32),256,0,stream>>>(Wi, Wi, nullptr, Sb, nullptr,
          nullptr, nullptr, nullptr, nullptr);
      kpinv<PM_M><<<dim3(4,4,32),256,0,stream>>>(Sb, Wi, nullptr, Mb, nullptr,
          Wi, Sb, nullptr, nullptr);
      kpinv<PM_PAIR><<<dim3(4,4,64),256,0,stream>>>(Wi, Mb, zi, Wo, zo,
          nullptr, nullptr, nullptr, nullptr);
      u16* t = Wi; Wi = Wo; Wo = t;
      zi = zo; zo = (zo == zA) ? zB : zA;
    }
    // thin tail: a=W5@w3, b=W5@a, c=W5@b (g1 = .25(13w3-15a+7b-c)); u=z5@g1*s0
    kpinv<PM_TH><<<dim3(4,1,32),256,0,stream>>>(Wi, w3T, nullptr, aT, nullptr,
        nullptr, nullptr, nullptr, nullptr);
    kpinv<PM_TH><<<dim3(4,1,32),256,0,stream>>>(Wi, aT, nullptr, bT, nullptr,
        nullptr, nullptr, nullptr, nullptr);
    kpinv<PM_THG><<<dim3(4,1,32),256,0,stream>>>(Wi, bT, nullptr, g1T, nullptr,
        w3T, aT, bT, nullptr);
    kpinv<PM_THINU><<<dim3(4,1,32),256,0,stream>>>(zi, g1T, nullptr, uT, nullptr,
        nullptr, nullptr, nullptr, scal);

    kattn1u<<<dim3(32,32),256,0,stream>>>(qb, kl, uT, vb, resw + i*264, aoutb);
    kgemm<EPI_BIAS_RES><<<dim3(128,4),256,0,stream>>>(aoutb, woutT + (long)i*65536, 256,256,256,
        bout + i*256, i==0 ? x : y, y, nullptr, 256);
    kln<<<4096,256,0,stream>>>(y, ln2g + i*256, ln2b + i*256, xn);
    kgemm2<EPI_BIAS_GELU><<<dim3(128,4),256,0,stream>>>(xn, w1T + (long)i*131072, 256, 256, 256,
        b1 + i*512, hdn, 512, nullptr,nullptr,nullptr, nullptr,nullptr);
    kgemm<EPI_BIAS_RES><<<dim3(128,4),256,0,stream>>>(hdn, w2T + (long)i*131072, 512,512,512,
        b2 + i*256, y, y, nullptr, 256);
  }
}